// Round 1
// baseline (369.643 us; speedup 1.0000x reference)
//
#include <hip/hip_runtime.h>

#define DEV __device__ __forceinline__

typedef unsigned short u16;
typedef __attribute__((ext_vector_type(8))) __bf16 bf16x8;
typedef __attribute__((ext_vector_type(4))) float f32x4;

DEV u16 f2bf(float f) {
  union { float f; unsigned u; } v; v.f = f;
  unsigned r = v.u + 0x7FFFu + ((v.u >> 16) & 1u);
  return (u16)(r >> 16);
}

template <typename T>
DEV void gload_lds16(const T* g, T* l) {
  __builtin_amdgcn_global_load_lds(
      (const __attribute__((address_space(1))) void*)(g),
      (__attribute__((address_space(3))) void*)(l),
      16, 0, 0);
}

DEV bf16x8 ldfrag(const u16* p) { return *(const bf16x8*)p; }

// ---------------- cast fp32 -> bf16, 8 elems/thread ----------------
__global__ __launch_bounds__(256) void cast_kernel(const float* __restrict__ in,
                                                   u16* __restrict__ out, int n8) {
  int i = blockIdx.x * blockDim.x + threadIdx.x;
  if (i >= n8) return;
  float4 a = ((const float4*)in)[2 * i];
  float4 b = ((const float4*)in)[2 * i + 1];
  uint4 o;
  o.x = (unsigned)f2bf(a.x) | ((unsigned)f2bf(a.y) << 16);
  o.y = (unsigned)f2bf(a.z) | ((unsigned)f2bf(a.w) << 16);
  o.z = (unsigned)f2bf(b.x) | ((unsigned)f2bf(b.y) << 16);
  o.w = (unsigned)f2bf(b.z) | ((unsigned)f2bf(b.w) << 16);
  ((uint4*)out)[i] = o;
}

// ---------------- fused QKV GEMM: [8192x1024] x W^T, m97-style ----------------
// grid (64, 24): x = row block (128 rows), y = col block (cb/8 -> Q/K/V, cb%8 -> 128 cols)
__global__ __launch_bounds__(256) void qkv_gemm(
    const u16* __restrict__ xb, const u16* __restrict__ wb,
    const float* __restrict__ bq, const float* __restrict__ bk, const float* __restrict__ bv,
    u16* __restrict__ qb, u16* __restrict__ kb, u16* __restrict__ vb) {
  __shared__ u16 As[128 * 64];
  __shared__ u16 Bs[128 * 64];
  const int t = threadIdx.x, lane = t & 63, w = t >> 6;
  const int wm = w >> 1, wn = w & 1;
  const int m0 = blockIdx.x * 128;
  const int cb = blockIdx.y;
  const int wsel = cb >> 3;
  const int n0 = (cb & 7) * 128;
  const u16* W = wb + wsel * (1024 * 1024);
  const float* bias = (wsel == 0) ? bq : (wsel == 1) ? bk : bv;
  u16* dst = (wsel == 0) ? qb : (wsel == 1) ? kb : vb;
  const float scale = (wsel == 0) ? 0.125f : 1.0f;

  f32x4 acc[4][4];
  const f32x4 z4 = {0.f, 0.f, 0.f, 0.f};
  for (int i = 0; i < 4; ++i)
    for (int j = 0; j < 4; ++j) acc[i][j] = z4;

  const int srow = w * 32 + (lane >> 3);   // +i*8
  const int scol = (lane & 7) * 8;

  for (int k0 = 0; k0 < 1024; k0 += 64) {
    __syncthreads();
    for (int i = 0; i < 4; ++i) {
      gload_lds16(xb + (m0 + srow + i * 8) * 1024 + k0 + scol, &As[w * 2048 + i * 512]);
      gload_lds16(W + (n0 + srow + i * 8) * 1024 + k0 + scol, &Bs[w * 2048 + i * 512]);
    }
    __syncthreads();
    for (int ks = 0; ks < 2; ++ks) {
      bf16x8 a[4], b[4];
      for (int mi = 0; mi < 4; ++mi)
        a[mi] = ldfrag(&As[(wm * 64 + mi * 16 + (lane & 15)) * 64 + ks * 32 + (lane >> 4) * 8]);
      for (int ni = 0; ni < 4; ++ni)
        b[ni] = ldfrag(&Bs[(wn * 64 + ni * 16 + (lane & 15)) * 64 + ks * 32 + (lane >> 4) * 8]);
      for (int mi = 0; mi < 4; ++mi)
        for (int ni = 0; ni < 4; ++ni)
          acc[mi][ni] = __builtin_amdgcn_mfma_f32_16x16x32_bf16(a[mi], b[ni], acc[mi][ni], 0, 0, 0);
    }
  }
  // epilogue: scale + bias, write bf16 into [N,H,L,D]
  for (int ni = 0; ni < 4; ++ni) {
    int col = n0 + wn * 64 + ni * 16 + (lane & 15);
    float bv_ = bias[col];
    int h = col >> 6, d = col & 63;
    for (int mi = 0; mi < 4; ++mi) {
      for (int r = 0; r < 4; ++r) {
        int gm = m0 + wm * 64 + mi * 16 + (lane >> 4) * 4 + r;
        int nn = gm >> 11, lq = gm & 2047;
        float val = acc[mi][ni][r] * scale + bv_;
        dst[(((nn << 4) + h) * 2048 + lq) * 64 + d] = f2bf(val);
      }
    }
  }
}

// ---------------- V transpose: [NH, L, D] -> [NH, D, L] ----------------
__global__ __launch_bounds__(256) void transpose_v(const u16* __restrict__ vb,
                                                   u16* __restrict__ vtb) {
  __shared__ u16 T[64][68];
  const int t = threadIdx.x;
  const int l0 = blockIdx.x * 64;
  const int head = blockIdx.y;
  const u16* src = vb + head * (2048 * 64) + l0 * 64;
  for (int c = t; c < 512; c += 256) {
    int l = c >> 3, dd = (c & 7) * 8;
    uint4 v = *(const uint4*)(src + l * 64 + dd);
    u16* d = &T[l][dd];
    ((uint2*)d)[0] = make_uint2(v.x, v.y);
    ((uint2*)d)[1] = make_uint2(v.z, v.w);
  }
  __syncthreads();
  u16* dsth = vtb + head * (64 * 2048);
  for (int c = t; c < 512; c += 256) {
    int d = c >> 3, lp = (c & 7) * 8;
    u16 tmp[8];
    for (int j = 0; j < 8; ++j) tmp[j] = T[lp + j][d];
    uint4 o;
    o.x = (unsigned)tmp[0] | ((unsigned)tmp[1] << 16);
    o.y = (unsigned)tmp[2] | ((unsigned)tmp[3] << 16);
    o.z = (unsigned)tmp[4] | ((unsigned)tmp[5] << 16);
    o.w = (unsigned)tmp[6] | ((unsigned)tmp[7] << 16);
    *(uint4*)(dsth + d * 2048 + l0 + lp) = o;
  }
}

// ---------------- flash attention ----------------
// grid (32, 64): x = q tile (64 rows), y = head (n*16+h). 4 waves, wave w owns q rows [w*16, w*16+16)
__global__ __launch_bounds__(256) void flash_attn(
    const u16* __restrict__ qb, const u16* __restrict__ kb, const u16* __restrict__ vtb,
    const float* __restrict__ mask, float* __restrict__ out) {
  __shared__ u16 Qs[64 * 64];
  __shared__ u16 Ks[64 * 64];
  __shared__ u16 Vs[64 * 64];   // transposed: [d][kv]
  __shared__ u16 Ps[4 * 16 * 64];

  const int t = threadIdx.x, lane = t & 63, w = t >> 6;
  const int q0 = blockIdx.x * 64;
  const int head = blockIdx.y;
  const int n = head >> 4, h = head & 15;

  const u16* qh = qb + head * (2048 * 64);
  const u16* kh = kb + head * (2048 * 64);
  const u16* vth = vtb + head * (64 * 2048);
  const float* mrow = mask + n * 2048;

  // stage Q tile (contiguous 8KB)
  {
    const u16* src = qh + q0 * 64;
    gload_lds16(src + w * 1024 + lane * 8, &Qs[w * 1024]);
    gload_lds16(src + w * 1024 + 512 + lane * 8, &Qs[w * 1024 + 512]);
  }
  __syncthreads();
  bf16x8 aq[2];
  for (int ks = 0; ks < 2; ++ks)
    aq[ks] = ldfrag(&Qs[(w * 16 + (lane & 15)) * 64 + ks * 32 + (lane >> 4) * 8]);

  const f32x4 z4 = {0.f, 0.f, 0.f, 0.f};
  f32x4 o[4];
  float m_[4], l_[4];
  for (int i = 0; i < 4; ++i) o[i] = z4;
  for (int r = 0; r < 4; ++r) { m_[r] = -1e30f; l_[r] = 0.f; }

  for (int kv0 = 0; kv0 < 2048; kv0 += 64) {
    __syncthreads();
    // stage K tile (contiguous) and Vt tile (rows d, stride 2048)
    {
      const u16* ksrc = kh + kv0 * 64;
      gload_lds16(ksrc + w * 1024 + lane * 8, &Ks[w * 1024]);
      gload_lds16(ksrc + w * 1024 + 512 + lane * 8, &Ks[w * 1024 + 512]);
      for (int i = 0; i < 2; ++i) {
        int dbase = w * 16 + i * 8;
        gload_lds16(vth + (dbase + (lane >> 3)) * 2048 + kv0 + (lane & 7) * 8, &Vs[dbase * 64]);
      }
    }
    __syncthreads();

    // S = Q K^T  (wave's 16 q-rows x 64 kv-cols)
    f32x4 s[4];
    for (int fc = 0; fc < 4; ++fc) {
      bf16x8 b0 = ldfrag(&Ks[(fc * 16 + (lane & 15)) * 64 + (lane >> 4) * 8]);
      bf16x8 b1 = ldfrag(&Ks[(fc * 16 + (lane & 15)) * 64 + 32 + (lane >> 4) * 8]);
      s[fc] = __builtin_amdgcn_mfma_f32_16x16x32_bf16(aq[0], b0, z4, 0, 0, 0);
      s[fc] = __builtin_amdgcn_mfma_f32_16x16x32_bf16(aq[1], b1, s[fc], 0, 0, 0);
    }

    // mask + online softmax (rows = (lane>>4)*4+r, cols spread over lanes&15 and fc)
    float pm[4];
    for (int r = 0; r < 4; ++r) pm[r] = -1e30f;
    for (int fc = 0; fc < 4; ++fc) {
      float mv = mrow[kv0 + fc * 16 + (lane & 15)];
      for (int r = 0; r < 4; ++r) {
        s[fc][r] += mv;
        pm[r] = fmaxf(pm[r], s[fc][r]);
      }
    }
    for (int off = 1; off < 16; off <<= 1)
      for (int r = 0; r < 4; ++r) pm[r] = fmaxf(pm[r], __shfl_xor(pm[r], off, 64));

    float sc[4], rs[4];
    for (int r = 0; r < 4; ++r) {
      float nm = fmaxf(m_[r], pm[r]);
      sc[r] = __expf(m_[r] - nm);
      m_[r] = nm;
      rs[r] = 0.f;
    }
    float p[4][4];
    for (int fc = 0; fc < 4; ++fc)
      for (int r = 0; r < 4; ++r) {
        float pv = __expf(s[fc][r] - m_[r]);
        p[fc][r] = pv;
        rs[r] += pv;
      }
    for (int off = 1; off < 16; off <<= 1)
      for (int r = 0; r < 4; ++r) rs[r] += __shfl_xor(rs[r], off, 64);
    for (int r = 0; r < 4; ++r) l_[r] = l_[r] * sc[r] + rs[r];
    for (int fc = 0; fc < 4; ++fc)
      for (int r = 0; r < 4; ++r) o[fc][r] *= sc[r];

    // P -> bf16 -> per-wave LDS (C-layout to A-layout relayout)
    u16* pw = &Ps[w * 1024];
    for (int fc = 0; fc < 4; ++fc)
      for (int r = 0; r < 4; ++r)
        pw[((lane >> 4) * 4 + r) * 64 + fc * 16 + (lane & 15)] = f2bf(p[fc][r]);
    asm volatile("s_waitcnt lgkmcnt(0)" ::: "memory");

    // O += P V
    bf16x8 pa0 = ldfrag(&pw[(lane & 15) * 64 + (lane >> 4) * 8]);
    bf16x8 pa1 = ldfrag(&pw[(lane & 15) * 64 + 32 + (lane >> 4) * 8]);
    for (int fc = 0; fc < 4; ++fc) {
      bf16x8 bv0 = ldfrag(&Vs[(fc * 16 + (lane & 15)) * 64 + (lane >> 4) * 8]);
      bf16x8 bv1 = ldfrag(&Vs[(fc * 16 + (lane & 15)) * 64 + 32 + (lane >> 4) * 8]);
      o[fc] = __builtin_amdgcn_mfma_f32_16x16x32_bf16(pa0, bv0, o[fc], 0, 0, 0);
      o[fc] = __builtin_amdgcn_mfma_f32_16x16x32_bf16(pa1, bv1, o[fc], 0, 0, 0);
    }
  }

  // epilogue: O / l, fp32 out [N, L, E]
  for (int r = 0; r < 4; ++r) {
    float inv = 1.0f / l_[r];
    int q = q0 + w * 16 + (lane >> 4) * 4 + r;
    for (int fc = 0; fc < 4; ++fc) {
      int d = fc * 16 + (lane & 15);
      out[(n * 2048 + q) * 1024 + h * 64 + d] = o[fc][r] * inv;
    }
  }
}

extern "C" void kernel_launch(void* const* d_in, const int* in_sizes, int n_in,
                              void* d_out, int out_size, void* d_ws, size_t ws_size,
                              hipStream_t stream) {
  const float* x = (const float*)d_in[0];
  const float* mask = (const float*)d_in[1];
  const float* Wq = (const float*)d_in[2];
  const float* bq = (const float*)d_in[3];
  const float* Wk = (const float*)d_in[4];
  const float* bk = (const float*)d_in[5];
  const float* Wv = (const float*)d_in[6];
  const float* bv = (const float*)d_in[7];
  float* out = (float*)d_out;

  u16* xb = (u16*)d_ws;                    // 8192*1024
  u16* wb = xb + 8192 * 1024;              // 3*1024*1024
  u16* qb = wb + 3 * 1024 * 1024;          // 64*2048*64 each
  u16* kb = qb + 64 * 2048 * 64;
  u16* vb = kb + 64 * 2048 * 64;
  u16* vtb = vb + 64 * 2048 * 64;

  cast_kernel<<<8192 * 1024 / 8 / 256, 256, 0, stream>>>(x, xb, 8192 * 1024 / 8);
  cast_kernel<<<1024 * 1024 / 8 / 256, 256, 0, stream>>>(Wq, wb, 1024 * 1024 / 8);
  cast_kernel<<<1024 * 1024 / 8 / 256, 256, 0, stream>>>(Wk, wb + 1024 * 1024, 1024 * 1024 / 8);
  cast_kernel<<<1024 * 1024 / 8 / 256, 256, 0, stream>>>(Wv, wb + 2 * 1024 * 1024, 1024 * 1024 / 8);
  qkv_gemm<<<dim3(64, 24), 256, 0, stream>>>(xb, wb, bq, bk, bv, qb, kb, vb);
  transpose_v<<<dim3(32, 64), 256, 0, stream>>>(vb, vtb);
  flash_attn<<<dim3(32, 64), 256, 0, stream>>>(qb, kb, vtb, mask, out);
}

// Round 2
// 304.290 us; speedup vs baseline: 1.2148x; 1.2148x over previous
//
#include <hip/hip_runtime.h>

#define DEV __device__ __forceinline__

typedef unsigned short u16;
typedef __attribute__((ext_vector_type(8))) __bf16 bf16x8;
typedef __attribute__((ext_vector_type(4))) float f32x4;

DEV u16 f2bf(float f) {
  union { float f; unsigned u; } v; v.f = f;
  unsigned r = v.u + 0x7FFFu + ((v.u >> 16) & 1u);
  return (u16)(r >> 16);
}

template <typename T>
DEV void gload_lds16(const T* g, T* l) {
  __builtin_amdgcn_global_load_lds(
      (const __attribute__((address_space(1))) void*)(g),
      (__attribute__((address_space(3))) void*)(l),
      16, 0, 0);
}

DEV bf16x8 ldfrag(const u16* p) { return *(const bf16x8*)p; }

// ---------------- cast fp32 -> bf16, 8 elems/thread ----------------
__global__ __launch_bounds__(256) void cast_kernel(const float* __restrict__ in,
                                                   u16* __restrict__ out, int n8) {
  int i = blockIdx.x * blockDim.x + threadIdx.x;
  if (i >= n8) return;
  float4 a = ((const float4*)in)[2 * i];
  float4 b = ((const float4*)in)[2 * i + 1];
  uint4 o;
  o.x = (unsigned)f2bf(a.x) | ((unsigned)f2bf(a.y) << 16);
  o.y = (unsigned)f2bf(a.z) | ((unsigned)f2bf(a.w) << 16);
  o.z = (unsigned)f2bf(b.x) | ((unsigned)f2bf(b.y) << 16);
  o.w = (unsigned)f2bf(b.z) | ((unsigned)f2bf(b.w) << 16);
  ((uint4*)out)[i] = o;
}

// ---------------- fused QKV GEMM: [8192x1024] x W^T, m97-style ----------------
// (2-phase structure: T2 swizzle is measured-null here, so tiles stay linear)
__global__ __launch_bounds__(256) void qkv_gemm(
    const u16* __restrict__ xb, const u16* __restrict__ wb,
    const float* __restrict__ bq, const float* __restrict__ bk, const float* __restrict__ bv,
    u16* __restrict__ qb, u16* __restrict__ kb, u16* __restrict__ vb) {
  __shared__ u16 As[128 * 64];
  __shared__ u16 Bs[128 * 64];
  const int t = threadIdx.x, lane = t & 63, w = t >> 6;
  const int wm = w >> 1, wn = w & 1;
  const int m0 = blockIdx.x * 128;
  const int cb = blockIdx.y;
  const int wsel = cb >> 3;
  const int n0 = (cb & 7) * 128;
  const u16* W = wb + wsel * (1024 * 1024);
  const float* bias = (wsel == 0) ? bq : (wsel == 1) ? bk : bv;
  u16* dst = (wsel == 0) ? qb : (wsel == 1) ? kb : vb;
  const float scale = (wsel == 0) ? 0.125f : 1.0f;

  f32x4 acc[4][4];
  const f32x4 z4 = {0.f, 0.f, 0.f, 0.f};
  for (int i = 0; i < 4; ++i)
    for (int j = 0; j < 4; ++j) acc[i][j] = z4;

  const int srow = w * 32 + (lane >> 3);   // +i*8
  const int scol = (lane & 7) * 8;

  for (int k0 = 0; k0 < 1024; k0 += 64) {
    __syncthreads();
    for (int i = 0; i < 4; ++i) {
      gload_lds16(xb + (m0 + srow + i * 8) * 1024 + k0 + scol, &As[w * 2048 + i * 512]);
      gload_lds16(W + (n0 + srow + i * 8) * 1024 + k0 + scol, &Bs[w * 2048 + i * 512]);
    }
    __syncthreads();
    for (int ks = 0; ks < 2; ++ks) {
      bf16x8 a[4], b[4];
      for (int mi = 0; mi < 4; ++mi)
        a[mi] = ldfrag(&As[(wm * 64 + mi * 16 + (lane & 15)) * 64 + ks * 32 + (lane >> 4) * 8]);
      for (int ni = 0; ni < 4; ++ni)
        b[ni] = ldfrag(&Bs[(wn * 64 + ni * 16 + (lane & 15)) * 64 + ks * 32 + (lane >> 4) * 8]);
      for (int mi = 0; mi < 4; ++mi)
        for (int ni = 0; ni < 4; ++ni)
          acc[mi][ni] = __builtin_amdgcn_mfma_f32_16x16x32_bf16(a[mi], b[ni], acc[mi][ni], 0, 0, 0);
    }
  }
  // epilogue: scale + bias, write bf16 into [N,H,L,D]
  for (int ni = 0; ni < 4; ++ni) {
    int col = n0 + wn * 64 + ni * 16 + (lane & 15);
    float bv_ = bias[col];
    int h = col >> 6, d = col & 63;
    for (int mi = 0; mi < 4; ++mi) {
      for (int r = 0; r < 4; ++r) {
        int gm = m0 + wm * 64 + mi * 16 + (lane >> 4) * 4 + r;
        int nn = gm >> 11, lq = gm & 2047;
        float val = acc[mi][ni][r] * scale + bv_;
        dst[(((nn << 4) + h) * 2048 + lq) * 64 + d] = f2bf(val);
      }
    }
  }
}

// ---------------- V transpose: [NH, L, D] -> [NH, D, L] ----------------
__global__ __launch_bounds__(256) void transpose_v(const u16* __restrict__ vb,
                                                   u16* __restrict__ vtb) {
  __shared__ u16 T[64][68];
  const int t = threadIdx.x;
  const int l0 = blockIdx.x * 64;
  const int head = blockIdx.y;
  const u16* src = vb + head * (2048 * 64) + l0 * 64;
  for (int c = t; c < 512; c += 256) {
    int l = c >> 3, dd = (c & 7) * 8;
    uint4 v = *(const uint4*)(src + l * 64 + dd);
    u16* d = &T[l][dd];
    ((uint2*)d)[0] = make_uint2(v.x, v.y);
    ((uint2*)d)[1] = make_uint2(v.z, v.w);
  }
  __syncthreads();
  u16* dsth = vtb + head * (64 * 2048);
  for (int c = t; c < 512; c += 256) {
    int d = c >> 3, lp = (c & 7) * 8;
    u16 tmp[8];
    for (int j = 0; j < 8; ++j) tmp[j] = T[lp + j][d];
    uint4 o;
    o.x = (unsigned)tmp[0] | ((unsigned)tmp[1] << 16);
    o.y = (unsigned)tmp[2] | ((unsigned)tmp[3] << 16);
    o.z = (unsigned)tmp[4] | ((unsigned)tmp[5] << 16);
    o.w = (unsigned)tmp[6] | ((unsigned)tmp[7] << 16);
    *(uint4*)(dsth + d * 2048 + l0 + lp) = o;
  }
}

// ---------------- flash attention (LDS tiles XOR-swizzled) ----------------
// All LDS tiles are [rows][64] bf16 (128B rows). Element e at (row, ce) is
// stored at (row, ce ^ ((row&7)<<3)) -- spreads the 16-way b128 row-stride
// bank conflict to 2-way (free). K/V/Q are staged with global_load_lds
// (linear LDS dest, rule #21), so the inverse swizzle is applied on the
// per-lane GLOBAL source address; P is reg-staged, swizzled on both sides.
__global__ __launch_bounds__(256) void flash_attn(
    const u16* __restrict__ qb, const u16* __restrict__ kb, const u16* __restrict__ vtb,
    const float* __restrict__ mask, float* __restrict__ out) {
  __shared__ u16 Qs[64 * 64];
  __shared__ u16 Ks[64 * 64];
  __shared__ u16 Vs[64 * 64];   // transposed: [d][kv]
  __shared__ u16 Ps[4 * 16 * 64];

  const int t = threadIdx.x, lane = t & 63, w = t >> 6;
  const int q0 = blockIdx.x * 64;
  const int head = blockIdx.y;
  const int n = head >> 4, h = head & 15;

  const u16* qh = qb + head * (2048 * 64);
  const u16* kh = kb + head * (2048 * 64);
  const u16* vth = vtb + head * (64 * 2048);
  const float* mrow = mask + n * 2048;

  // staging geometry: one gload_lds16 call covers 1024B = 8 rows of 128B.
  // lane -> row_local = lane>>3, source col = 8*((lane&7) ^ row_local)  (inverse swizzle)
  const int srow8 = lane >> 3;                 // 0..7
  const int scolsw = (((lane & 7) ^ srow8) * 8);
  // read-side swizzle term for fragment reads (row&7 == lane&7 for all our reads)
  const int rsw = (lane & 7) * 8;
  const int fcol0 = ((lane >> 4) * 8) ^ rsw;          // ks=0 fragment col
  const int fcol1 = (32 + (lane >> 4) * 8) ^ rsw;     // ks=1 fragment col

  // stage Q tile (rows w*16 .. w*16+15)
  {
    const u16* src = qh + q0 * 64;
    gload_lds16(src + (w * 16 + srow8) * 64 + scolsw, &Qs[w * 1024]);
    gload_lds16(src + (w * 16 + 8 + srow8) * 64 + scolsw, &Qs[w * 1024 + 512]);
  }
  __syncthreads();
  bf16x8 aq[2];
  aq[0] = ldfrag(&Qs[(w * 16 + (lane & 15)) * 64 + fcol0]);
  aq[1] = ldfrag(&Qs[(w * 16 + (lane & 15)) * 64 + fcol1]);

  const f32x4 z4 = {0.f, 0.f, 0.f, 0.f};
  f32x4 o[4];
  float m_[4], l_[4];
  for (int i = 0; i < 4; ++i) o[i] = z4;
  for (int r = 0; r < 4; ++r) { m_[r] = -1e30f; l_[r] = 0.f; }

  for (int kv0 = 0; kv0 < 2048; kv0 += 64) {
    __syncthreads();
    // stage K tile (rows = kv) and Vt tile (rows = d), swizzled sources
    {
      const u16* ksrc = kh + kv0 * 64;
      gload_lds16(ksrc + (w * 16 + srow8) * 64 + scolsw, &Ks[w * 1024]);
      gload_lds16(ksrc + (w * 16 + 8 + srow8) * 64 + scolsw, &Ks[w * 1024 + 512]);
      for (int i = 0; i < 2; ++i) {
        int dbase = w * 16 + i * 8;
        gload_lds16(vth + (dbase + srow8) * 2048 + kv0 + scolsw, &Vs[dbase * 64]);
      }
    }
    __syncthreads();

    // S = Q K^T  (wave's 16 q-rows x 64 kv-cols)
    f32x4 s[4];
    for (int fc = 0; fc < 4; ++fc) {
      bf16x8 b0 = ldfrag(&Ks[(fc * 16 + (lane & 15)) * 64 + fcol0]);
      bf16x8 b1 = ldfrag(&Ks[(fc * 16 + (lane & 15)) * 64 + fcol1]);
      s[fc] = __builtin_amdgcn_mfma_f32_16x16x32_bf16(aq[0], b0, z4, 0, 0, 0);
      s[fc] = __builtin_amdgcn_mfma_f32_16x16x32_bf16(aq[1], b1, s[fc], 0, 0, 0);
    }

    // mask + online softmax (rows = (lane>>4)*4+r, cols spread over lanes&15 and fc)
    float pm[4];
    for (int r = 0; r < 4; ++r) pm[r] = -1e30f;
    for (int fc = 0; fc < 4; ++fc) {
      float mv = mrow[kv0 + fc * 16 + (lane & 15)];
      for (int r = 0; r < 4; ++r) {
        s[fc][r] += mv;
        pm[r] = fmaxf(pm[r], s[fc][r]);
      }
    }
    for (int off = 1; off < 16; off <<= 1)
      for (int r = 0; r < 4; ++r) pm[r] = fmaxf(pm[r], __shfl_xor(pm[r], off, 64));

    float sc[4], rs[4];
    for (int r = 0; r < 4; ++r) {
      float nm = fmaxf(m_[r], pm[r]);
      sc[r] = __expf(m_[r] - nm);
      m_[r] = nm;
      rs[r] = 0.f;
    }
    float p[4][4];
    for (int fc = 0; fc < 4; ++fc)
      for (int r = 0; r < 4; ++r) {
        float pv = __expf(s[fc][r] - m_[r]);
        p[fc][r] = pv;
        rs[r] += pv;
      }
    for (int off = 1; off < 16; off <<= 1)
      for (int r = 0; r < 4; ++r) rs[r] += __shfl_xor(rs[r], off, 64);
    for (int r = 0; r < 4; ++r) l_[r] = l_[r] * sc[r] + rs[r];
    for (int fc = 0; fc < 4; ++fc)
      for (int r = 0; r < 4; ++r) o[fc][r] *= sc[r];

    // P -> bf16 -> per-wave LDS (C-layout to A-layout relayout), swizzled
    u16* pw = &Ps[w * 1024];
    for (int fc = 0; fc < 4; ++fc)
      for (int r = 0; r < 4; ++r) {
        int pr = (lane >> 4) * 4 + r;
        int ce = fc * 16 + (lane & 15);
        pw[pr * 64 + (ce ^ ((pr & 7) * 8))] = f2bf(p[fc][r]);
      }
    asm volatile("s_waitcnt lgkmcnt(0)" ::: "memory");

    // O += P V  (P read swizzled: row = lane&15 -> row&7 == lane&7)
    bf16x8 pa0 = ldfrag(&pw[(lane & 15) * 64 + fcol0]);
    bf16x8 pa1 = ldfrag(&pw[(lane & 15) * 64 + fcol1]);
    for (int fc = 0; fc < 4; ++fc) {
      bf16x8 bv0 = ldfrag(&Vs[(fc * 16 + (lane & 15)) * 64 + fcol0]);
      bf16x8 bv1 = ldfrag(&Vs[(fc * 16 + (lane & 15)) * 64 + fcol1]);
      o[fc] = __builtin_amdgcn_mfma_f32_16x16x32_bf16(pa0, bv0, o[fc], 0, 0, 0);
      o[fc] = __builtin_amdgcn_mfma_f32_16x16x32_bf16(pa1, bv1, o[fc], 0, 0, 0);
    }
  }

  // epilogue: O / l, fp32 out [N, L, E]
  for (int r = 0; r < 4; ++r) {
    float inv = 1.0f / l_[r];
    int q = q0 + w * 16 + (lane >> 4) * 4 + r;
    for (int fc = 0; fc < 4; ++fc) {
      int d = fc * 16 + (lane & 15);
      out[(n * 2048 + q) * 1024 + h * 64 + d] = o[fc][r] * inv;
    }
  }
}

extern "C" void kernel_launch(void* const* d_in, const int* in_sizes, int n_in,
                              void* d_out, int out_size, void* d_ws, size_t ws_size,
                              hipStream_t stream) {
  const float* x = (const float*)d_in[0];
  const float* mask = (const float*)d_in[1];
  const float* Wq = (const float*)d_in[2];
  const float* bq = (const float*)d_in[3];
  const float* Wk = (const float*)d_in[4];
  const float* bk = (const float*)d_in[5];
  const float* Wv = (const float*)d_in[6];
  const float* bv = (const float*)d_in[7];
  float* out = (float*)d_out;

  u16* xb = (u16*)d_ws;                    // 8192*1024
  u16* wb = xb + 8192 * 1024;              // 3*1024*1024
  u16* qb = wb + 3 * 1024 * 1024;          // 64*2048*64 each
  u16* kb = qb + 64 * 2048 * 64;
  u16* vb = kb + 64 * 2048 * 64;
  u16* vtb = vb + 64 * 2048 * 64;

  cast_kernel<<<8192 * 1024 / 8 / 256, 256, 0, stream>>>(x, xb, 8192 * 1024 / 8);
  cast_kernel<<<1024 * 1024 / 8 / 256, 256, 0, stream>>>(Wq, wb, 1024 * 1024 / 8);
  cast_kernel<<<1024 * 1024 / 8 / 256, 256, 0, stream>>>(Wk, wb + 1024 * 1024, 1024 * 1024 / 8);
  cast_kernel<<<1024 * 1024 / 8 / 256, 256, 0, stream>>>(Wv, wb + 2 * 1024 * 1024, 1024 * 1024 / 8);
  qkv_gemm<<<dim3(64, 24), 256, 0, stream>>>(xb, wb, bq, bk, bv, qb, kb, vb);
  transpose_v<<<dim3(32, 64), 256, 0, stream>>>(vb, vtb);
  flash_attn<<<dim3(32, 64), 256, 0, stream>>>(qb, kb, vtb, mask, out);
}

// Round 3
// 242.673 us; speedup vs baseline: 1.5232x; 1.2539x over previous
//
#include <hip/hip_runtime.h>

#define DEV __device__ __forceinline__

typedef unsigned short u16;
typedef __attribute__((ext_vector_type(8))) __bf16 bf16x8;
typedef __attribute__((ext_vector_type(4))) float f32x4;

#define LOG2E 1.44269504088896340736f

DEV u16 f2bf(float f) {
  union { float f; unsigned u; } v; v.f = f;
  unsigned r = v.u + 0x7FFFu + ((v.u >> 16) & 1u);
  return (u16)(r >> 16);
}

DEV float exp2_fast(float x) {
#if __has_builtin(__builtin_amdgcn_exp2f)
  return __builtin_amdgcn_exp2f(x);
#else
  float r;
  asm volatile("v_exp_f32 %0, %1" : "=v"(r) : "v"(x));
  return r;
#endif
}

template <typename T>
DEV void gload_lds16(const T* g, T* l) {
  __builtin_amdgcn_global_load_lds(
      (const __attribute__((address_space(1))) void*)(g),
      (__attribute__((address_space(3))) void*)(l),
      16, 0, 0);
}

DEV bf16x8 ldfrag(const u16* p) { return *(const bf16x8*)p; }

// ---------------- cast fp32 -> bf16, 8 elems/thread ----------------
__global__ __launch_bounds__(256) void cast_kernel(const float* __restrict__ in,
                                                   u16* __restrict__ out, int n8) {
  int i = blockIdx.x * blockDim.x + threadIdx.x;
  if (i >= n8) return;
  float4 a = ((const float4*)in)[2 * i];
  float4 b = ((const float4*)in)[2 * i + 1];
  uint4 o;
  o.x = (unsigned)f2bf(a.x) | ((unsigned)f2bf(a.y) << 16);
  o.y = (unsigned)f2bf(a.z) | ((unsigned)f2bf(a.w) << 16);
  o.z = (unsigned)f2bf(b.x) | ((unsigned)f2bf(b.y) << 16);
  o.w = (unsigned)f2bf(b.z) | ((unsigned)f2bf(b.w) << 16);
  ((uint4*)out)[i] = o;
}

// ---------------- fused QKV GEMM: [8192x1024] x W^T, m97-style ----------------
__global__ __launch_bounds__(256) void qkv_gemm(
    const u16* __restrict__ xb, const u16* __restrict__ wb,
    const float* __restrict__ bq, const float* __restrict__ bk, const float* __restrict__ bv,
    u16* __restrict__ qb, u16* __restrict__ kb, u16* __restrict__ vb) {
  __shared__ u16 As[128 * 64];
  __shared__ u16 Bs[128 * 64];
  const int t = threadIdx.x, lane = t & 63, w = t >> 6;
  const int wm = w >> 1, wn = w & 1;
  const int m0 = blockIdx.x * 128;
  const int cb = blockIdx.y;
  const int wsel = cb >> 3;
  const int n0 = (cb & 7) * 128;
  const u16* W = wb + wsel * (1024 * 1024);
  const float* bias = (wsel == 0) ? bq : (wsel == 1) ? bk : bv;
  u16* dst = (wsel == 0) ? qb : (wsel == 1) ? kb : vb;
  // Q gets 1/sqrt(D) AND log2(e) folded in (attention uses exp2 directly)
  const float scale = (wsel == 0) ? 0.125f * LOG2E : 1.0f;

  f32x4 acc[4][4];
  const f32x4 z4 = {0.f, 0.f, 0.f, 0.f};
  for (int i = 0; i < 4; ++i)
    for (int j = 0; j < 4; ++j) acc[i][j] = z4;

  const int srow = w * 32 + (lane >> 3);   // +i*8
  const int scol = (lane & 7) * 8;

  for (int k0 = 0; k0 < 1024; k0 += 64) {
    __syncthreads();
    for (int i = 0; i < 4; ++i) {
      gload_lds16(xb + (m0 + srow + i * 8) * 1024 + k0 + scol, &As[w * 2048 + i * 512]);
      gload_lds16(W + (n0 + srow + i * 8) * 1024 + k0 + scol, &Bs[w * 2048 + i * 512]);
    }
    __syncthreads();
    for (int ks = 0; ks < 2; ++ks) {
      bf16x8 a[4], b[4];
      for (int mi = 0; mi < 4; ++mi)
        a[mi] = ldfrag(&As[(wm * 64 + mi * 16 + (lane & 15)) * 64 + ks * 32 + (lane >> 4) * 8]);
      for (int ni = 0; ni < 4; ++ni)
        b[ni] = ldfrag(&Bs[(wn * 64 + ni * 16 + (lane & 15)) * 64 + ks * 32 + (lane >> 4) * 8]);
      for (int mi = 0; mi < 4; ++mi)
        for (int ni = 0; ni < 4; ++ni)
          acc[mi][ni] = __builtin_amdgcn_mfma_f32_16x16x32_bf16(a[mi], b[ni], acc[mi][ni], 0, 0, 0);
    }
  }
  // epilogue: scale + bias, write bf16 into [N,H,L,D]
  for (int ni = 0; ni < 4; ++ni) {
    int col = n0 + wn * 64 + ni * 16 + (lane & 15);
    float bv_ = bias[col];
    int h = col >> 6, d = col & 63;
    for (int mi = 0; mi < 4; ++mi) {
      for (int r = 0; r < 4; ++r) {
        int gm = m0 + wm * 64 + mi * 16 + (lane >> 4) * 4 + r;
        int nn = gm >> 11, lq = gm & 2047;
        float val = acc[mi][ni][r] * scale + bv_;
        dst[(((nn << 4) + h) * 2048 + lq) * 64 + d] = f2bf(val);
      }
    }
  }
}

// ---------------- V transpose: [NH, L, D] -> [NH, D, L] ----------------
__global__ __launch_bounds__(256) void transpose_v(const u16* __restrict__ vb,
                                                   u16* __restrict__ vtb) {
  __shared__ u16 T[64][68];
  const int t = threadIdx.x;
  const int l0 = blockIdx.x * 64;
  const int head = blockIdx.y;
  const u16* src = vb + head * (2048 * 64) + l0 * 64;
  for (int c = t; c < 512; c += 256) {
    int l = c >> 3, dd = (c & 7) * 8;
    uint4 v = *(const uint4*)(src + l * 64 + dd);
    u16* d = &T[l][dd];
    ((uint2*)d)[0] = make_uint2(v.x, v.y);
    ((uint2*)d)[1] = make_uint2(v.z, v.w);
  }
  __syncthreads();
  u16* dsth = vtb + head * (64 * 2048);
  for (int c = t; c < 512; c += 256) {
    int d = c >> 3, lp = (c & 7) * 8;
    u16 tmp[8];
    for (int j = 0; j < 8; ++j) tmp[j] = T[lp + j][d];
    uint4 o;
    o.x = (unsigned)tmp[0] | ((unsigned)tmp[1] << 16);
    o.y = (unsigned)tmp[2] | ((unsigned)tmp[3] << 16);
    o.z = (unsigned)tmp[4] | ((unsigned)tmp[5] << 16);
    o.w = (unsigned)tmp[6] | ((unsigned)tmp[7] << 16);
    *(uint4*)(dsth + d * 2048 + l0 + lp) = o;
  }
}

// ---------------- flash attention ----------------
// XOR-swizzled LDS (round-2, kept: bank conflicts == 0).  New this round:
//  - K/V double-buffered; STAGE(t+1) issued BEFORE compute(t); ONE barrier/tile
//  - P LDS aliased onto the dead Q tile (40KB total -> 4 blocks/CU)
//  - deferred sum (l kept as per-lane partials, reduced once in epilogue)
//  - defer-max THR=8 (T13): skip max-reduce+rescale when __all(pml <= m+8)
//  - exp2 direct (log2e folded into Q scale & mask)
__global__ __launch_bounds__(256) void flash_attn(
    const u16* __restrict__ qb, const u16* __restrict__ kb, const u16* __restrict__ vtb,
    const float* __restrict__ mask, float* __restrict__ out) {
  __shared__ u16 Qs[64 * 64];          // Q tile; reused as per-wave P after prologue
  __shared__ u16 Ks[2][64 * 64];
  __shared__ u16 Vs[2][64 * 64];       // transposed: [d][kv]

  const int t = threadIdx.x, lane = t & 63, w = t >> 6;
  const int q0 = blockIdx.x * 64;
  const int head = blockIdx.y;
  const int n = head >> 4, h = head & 15;

  const u16* qh = qb + head * (2048 * 64);
  const u16* kh = kb + head * (2048 * 64);
  const u16* vth = vtb + head * (64 * 2048);
  const float* mrow = mask + n * 2048;

  // staging geometry: one gload_lds16 covers 1024B = 8 rows of 128B.
  const int srow8 = lane >> 3;                   // 0..7
  const int scolsw = (((lane & 7) ^ srow8) * 8); // inverse-swizzled source col
  // read-side swizzle term (row&7 == lane&7 for all fragment reads)
  const int rsw = (lane & 7) * 8;
  const int fcol0 = ((lane >> 4) * 8) ^ rsw;
  const int fcol1 = (32 + (lane >> 4) * 8) ^ rsw;

  // prologue: stage Q tile + K/V tile 0 (buffer 0)
  {
    const u16* src = qh + q0 * 64;
    gload_lds16(src + (w * 16 + srow8) * 64 + scolsw, &Qs[w * 1024]);
    gload_lds16(src + (w * 16 + 8 + srow8) * 64 + scolsw, &Qs[w * 1024 + 512]);
    const u16* ksrc = kh;
    gload_lds16(ksrc + (w * 16 + srow8) * 64 + scolsw, &Ks[0][w * 1024]);
    gload_lds16(ksrc + (w * 16 + 8 + srow8) * 64 + scolsw, &Ks[0][w * 1024 + 512]);
    for (int i = 0; i < 2; ++i) {
      int dbase = w * 16 + i * 8;
      gload_lds16(vth + (dbase + srow8) * 2048 + scolsw, &Vs[0][dbase * 64]);
    }
  }
  __syncthreads();
  bf16x8 aq[2];
  aq[0] = ldfrag(&Qs[(w * 16 + (lane & 15)) * 64 + fcol0]);
  aq[1] = ldfrag(&Qs[(w * 16 + (lane & 15)) * 64 + fcol1]);
  // Qs is now dead; wave w's region becomes its private P buffer
  u16* pw = &Qs[w * 1024];
  __bf16* pwb = (__bf16*)pw;

  const f32x4 z4 = {0.f, 0.f, 0.f, 0.f};
  f32x4 o[4];
  float m_[4], lp_[4];
  for (int i = 0; i < 4; ++i) o[i] = z4;
  for (int r = 0; r < 4; ++r) { m_[r] = -1e30f; lp_[r] = 0.f; }

  for (int tt = 0; tt < 32; ++tt) {
    const int cur = tt & 1;
    const int kv0 = tt * 64;
    // STAGE(t+1) into the other buffer -- overlaps with compute below
    if (tt < 31) {
      const int kv1 = kv0 + 64;
      const u16* ksrc = kh + kv1 * 64;
      gload_lds16(ksrc + (w * 16 + srow8) * 64 + scolsw, &Ks[cur ^ 1][w * 1024]);
      gload_lds16(ksrc + (w * 16 + 8 + srow8) * 64 + scolsw, &Ks[cur ^ 1][w * 1024 + 512]);
      for (int i = 0; i < 2; ++i) {
        int dbase = w * 16 + i * 8;
        gload_lds16(vth + (dbase + srow8) * 2048 + kv1 + scolsw, &Vs[cur ^ 1][dbase * 64]);
      }
    }
    const u16* Kc = Ks[cur];
    const u16* Vc = Vs[cur];

    // mask loads early (latency hides under MFMA)
    float mvv[4];
    for (int fc = 0; fc < 4; ++fc)
      mvv[fc] = mrow[kv0 + fc * 16 + (lane & 15)] * LOG2E;

    // S = Q K^T (wave's 16 q-rows x 64 kv-cols), log2 domain
    f32x4 s[4];
    for (int fc = 0; fc < 4; ++fc) {
      bf16x8 b0 = ldfrag(&Kc[(fc * 16 + (lane & 15)) * 64 + fcol0]);
      bf16x8 b1 = ldfrag(&Kc[(fc * 16 + (lane & 15)) * 64 + fcol1]);
      s[fc] = __builtin_amdgcn_mfma_f32_16x16x32_bf16(aq[0], b0, z4, 0, 0, 0);
      s[fc] = __builtin_amdgcn_mfma_f32_16x16x32_bf16(aq[1], b1, s[fc], 0, 0, 0);
    }

    // mask add + per-lane local max
    float pml[4];
    for (int r = 0; r < 4; ++r) pml[r] = -1e30f;
    for (int fc = 0; fc < 4; ++fc)
      for (int r = 0; r < 4; ++r) {
        s[fc][r] += mvv[fc];
        pml[r] = fmaxf(pml[r], s[fc][r]);
      }

    // defer-max: full reduce+rescale only when some row grew past m+8
    int ok = (pml[0] <= m_[0] + 8.f) && (pml[1] <= m_[1] + 8.f) &&
             (pml[2] <= m_[2] + 8.f) && (pml[3] <= m_[3] + 8.f);
    if (!__all(ok)) {
      float pm[4];
      for (int r = 0; r < 4; ++r) pm[r] = pml[r];
      for (int off = 1; off < 16; off <<= 1)
        for (int r = 0; r < 4; ++r) pm[r] = fmaxf(pm[r], __shfl_xor(pm[r], off, 64));
      for (int r = 0; r < 4; ++r) {
        float nm = fmaxf(m_[r], pm[r]);
        float sc = exp2_fast(m_[r] - nm);
        m_[r] = nm;
        lp_[r] *= sc;
        for (int fc = 0; fc < 4; ++fc) o[fc][r] *= sc;
      }
    }

    // P = exp2(S - m): write bf16 to per-wave LDS (swizzled), accumulate partial l
    for (int fc = 0; fc < 4; ++fc)
      for (int r = 0; r < 4; ++r) {
        float pv = exp2_fast(s[fc][r] - m_[r]);
        lp_[r] += pv;
        int pr = (lane >> 4) * 4 + r;
        int ce = fc * 16 + (lane & 15);
        pwb[pr * 64 + (ce ^ ((pr & 7) * 8))] = (__bf16)pv;
      }
    asm volatile("s_waitcnt lgkmcnt(0)" ::: "memory");

    // O += P V
    bf16x8 pa0 = ldfrag(&pw[(lane & 15) * 64 + fcol0]);
    bf16x8 pa1 = ldfrag(&pw[(lane & 15) * 64 + fcol1]);
    for (int fc = 0; fc < 4; ++fc) {
      bf16x8 bv0 = ldfrag(&Vc[(fc * 16 + (lane & 15)) * 64 + fcol0]);
      bf16x8 bv1 = ldfrag(&Vc[(fc * 16 + (lane & 15)) * 64 + fcol1]);
      o[fc] = __builtin_amdgcn_mfma_f32_16x16x32_bf16(pa0, bv0, o[fc], 0, 0, 0);
      o[fc] = __builtin_amdgcn_mfma_f32_16x16x32_bf16(pa1, bv1, o[fc], 0, 0, 0);
    }

    if (tt < 31) __syncthreads();   // drains vmcnt: next buffer fully staged
  }

  // epilogue: reduce partial l across the 16-lane column group, then O / l
  for (int off = 1; off < 16; off <<= 1)
    for (int r = 0; r < 4; ++r) lp_[r] += __shfl_xor(lp_[r], off, 64);
  for (int r = 0; r < 4; ++r) {
    float inv = 1.0f / lp_[r];
    int q = q0 + w * 16 + (lane >> 4) * 4 + r;
    for (int fc = 0; fc < 4; ++fc) {
      int d = fc * 16 + (lane & 15);
      out[(n * 2048 + q) * 1024 + h * 64 + d] = o[fc][r] * inv;
    }
  }
}

extern "C" void kernel_launch(void* const* d_in, const int* in_sizes, int n_in,
                              void* d_out, int out_size, void* d_ws, size_t ws_size,
                              hipStream_t stream) {
  const float* x = (const float*)d_in[0];
  const float* mask = (const float*)d_in[1];
  const float* Wq = (const float*)d_in[2];
  const float* bq = (const float*)d_in[3];
  const float* Wk = (const float*)d_in[4];
  const float* bk = (const float*)d_in[5];
  const float* Wv = (const float*)d_in[6];
  const float* bv = (const float*)d_in[7];
  float* out = (float*)d_out;

  u16* xb = (u16*)d_ws;                    // 8192*1024
  u16* wb = xb + 8192 * 1024;              // 3*1024*1024
  u16* qb = wb + 3 * 1024 * 1024;          // 64*2048*64 each
  u16* kb = qb + 64 * 2048 * 64;
  u16* vb = kb + 64 * 2048 * 64;
  u16* vtb = vb + 64 * 2048 * 64;

  cast_kernel<<<8192 * 1024 / 8 / 256, 256, 0, stream>>>(x, xb, 8192 * 1024 / 8);
  cast_kernel<<<1024 * 1024 / 8 / 256, 256, 0, stream>>>(Wq, wb, 1024 * 1024 / 8);
  cast_kernel<<<1024 * 1024 / 8 / 256, 256, 0, stream>>>(Wk, wb + 1024 * 1024, 1024 * 1024 / 8);
  cast_kernel<<<1024 * 1024 / 8 / 256, 256, 0, stream>>>(Wv, wb + 2 * 1024 * 1024, 1024 * 1024 / 8);
  qkv_gemm<<<dim3(64, 24), 256, 0, stream>>>(xb, wb, bq, bk, bv, qb, kb, vb);
  transpose_v<<<dim3(32, 64), 256, 0, stream>>>(vb, vtb);
  flash_attn<<<dim3(32, 64), 256, 0, stream>>>(qb, kb, vtb, mask, out);
}

// Round 5
// 217.759 us; speedup vs baseline: 1.6975x; 1.1144x over previous
//
#include <hip/hip_runtime.h>

#define DEV __device__ __forceinline__

typedef unsigned short u16;
typedef __attribute__((ext_vector_type(8))) __bf16 bf16x8;
typedef __attribute__((ext_vector_type(4))) float f32x4;
typedef __attribute__((ext_vector_type(16))) float f32x16;

#define LOG2E 1.44269504088896340736f

DEV u16 f2bf(float f) {
  union { float f; unsigned u; } v; v.f = f;
  unsigned r = v.u + 0x7FFFu + ((v.u >> 16) & 1u);
  return (u16)(r >> 16);
}

DEV float exp2_fast(float x) {
#if __has_builtin(__builtin_amdgcn_exp2f)
  return __builtin_amdgcn_exp2f(x);
#else
  float r;
  asm volatile("v_exp_f32 %0, %1" : "=v"(r) : "v"(x));
  return r;
#endif
}

// partner (lane^32) exchange -- known semantics (compiles to ds_bpermute/permlane)
DEV float xor32_f(float v) { return __shfl_xor(v, 32, 64); }
DEV unsigned xor32_u(unsigned v) {
  return (unsigned)__shfl_xor((int)v, 32, 64);
}
DEV unsigned cvtpk(float lo, float hi) {
  unsigned r;
  asm volatile("v_cvt_pk_bf16_f32 %0, %1, %2" : "=v"(r) : "v"(lo), "v"(hi));
  return r;
}
DEV float bperm_f(int srclane, float v) {
  union { float f; int i; } u;
  u.f = v;
  u.i = __builtin_amdgcn_ds_bpermute(srclane * 4, u.i);
  return u.f;
}

template <typename T>
DEV void gload_lds16(const T* g, T* l) {
  __builtin_amdgcn_global_load_lds(
      (const __attribute__((address_space(1))) void*)(g),
      (__attribute__((address_space(3))) void*)(l),
      16, 0, 0);
}

DEV bf16x8 ldfrag(const u16* p) { return *(const bf16x8*)p; }

// ---------------- cast fp32 -> bf16, 8 elems/thread ----------------
__global__ __launch_bounds__(256) void cast_kernel(const float* __restrict__ in,
                                                   u16* __restrict__ out, int n8) {
  int i = blockIdx.x * blockDim.x + threadIdx.x;
  if (i >= n8) return;
  float4 a = ((const float4*)in)[2 * i];
  float4 b = ((const float4*)in)[2 * i + 1];
  uint4 o;
  o.x = (unsigned)f2bf(a.x) | ((unsigned)f2bf(a.y) << 16);
  o.y = (unsigned)f2bf(a.z) | ((unsigned)f2bf(a.w) << 16);
  o.z = (unsigned)f2bf(b.x) | ((unsigned)f2bf(b.y) << 16);
  o.w = (unsigned)f2bf(b.z) | ((unsigned)f2bf(b.w) << 16);
  ((uint4*)out)[i] = o;
}

// ---------------- mask * log2(e) ----------------
__global__ __launch_bounds__(256) void mask_scale(const float* __restrict__ in,
                                                  float* __restrict__ outp, int n) {
  int i = blockIdx.x * blockDim.x + threadIdx.x;
  if (i < n) outp[i] = in[i] * LOG2E;
}

// ---------------- fused QKV GEMM: [8192x1024] x W^T, m97-style ----------------
__global__ __launch_bounds__(256) void qkv_gemm(
    const u16* __restrict__ xb, const u16* __restrict__ wb,
    const float* __restrict__ bq, const float* __restrict__ bk, const float* __restrict__ bv,
    u16* __restrict__ qb, u16* __restrict__ kb, u16* __restrict__ vb) {
  __shared__ u16 As[128 * 64];
  __shared__ u16 Bs[128 * 64];
  const int t = threadIdx.x, lane = t & 63, w = t >> 6;
  const int wm = w >> 1, wn = w & 1;
  const int m0 = blockIdx.x * 128;
  const int cb = blockIdx.y;
  const int wsel = cb >> 3;
  const int n0 = (cb & 7) * 128;
  const u16* W = wb + wsel * (1024 * 1024);
  const float* bias = (wsel == 0) ? bq : (wsel == 1) ? bk : bv;
  u16* dst = (wsel == 0) ? qb : (wsel == 1) ? kb : vb;
  // Q gets 1/sqrt(D) AND log2(e) folded in (attention uses exp2 directly)
  const float scale = (wsel == 0) ? 0.125f * LOG2E : 1.0f;

  f32x4 acc[4][4];
  const f32x4 z4 = {0.f, 0.f, 0.f, 0.f};
  for (int i = 0; i < 4; ++i)
    for (int j = 0; j < 4; ++j) acc[i][j] = z4;

  const int srow = w * 32 + (lane >> 3);   // +i*8
  const int scol = (lane & 7) * 8;

  for (int k0 = 0; k0 < 1024; k0 += 64) {
    __syncthreads();
    for (int i = 0; i < 4; ++i) {
      gload_lds16(xb + (m0 + srow + i * 8) * 1024 + k0 + scol, &As[w * 2048 + i * 512]);
      gload_lds16(W + (n0 + srow + i * 8) * 1024 + k0 + scol, &Bs[w * 2048 + i * 512]);
    }
    __syncthreads();
    for (int ks = 0; ks < 2; ++ks) {
      bf16x8 a[4], b[4];
      for (int mi = 0; mi < 4; ++mi)
        a[mi] = ldfrag(&As[(wm * 64 + mi * 16 + (lane & 15)) * 64 + ks * 32 + (lane >> 4) * 8]);
      for (int ni = 0; ni < 4; ++ni)
        b[ni] = ldfrag(&Bs[(wn * 64 + ni * 16 + (lane & 15)) * 64 + ks * 32 + (lane >> 4) * 8]);
      for (int mi = 0; mi < 4; ++mi)
        for (int ni = 0; ni < 4; ++ni)
          acc[mi][ni] = __builtin_amdgcn_mfma_f32_16x16x32_bf16(a[mi], b[ni], acc[mi][ni], 0, 0, 0);
    }
  }
  // epilogue: scale + bias, write bf16 into [N,H,L,D]
  for (int ni = 0; ni < 4; ++ni) {
    int col = n0 + wn * 64 + ni * 16 + (lane & 15);
    float bv_ = bias[col];
    int h = col >> 6, d = col & 63;
    for (int mi = 0; mi < 4; ++mi) {
      for (int r = 0; r < 4; ++r) {
        int gm = m0 + wm * 64 + mi * 16 + (lane >> 4) * 4 + r;
        int nn = gm >> 11, lq = gm & 2047;
        float val = acc[mi][ni][r] * scale + bv_;
        dst[(((nn << 4) + h) * 2048 + lq) * 64 + d] = f2bf(val);
      }
    }
  }
}

// ---------------- V transpose: [NH, L, D] -> [NH, D, L] ----------------
__global__ __launch_bounds__(256) void transpose_v(const u16* __restrict__ vb,
                                                   u16* __restrict__ vtb) {
  __shared__ u16 T[64][68];
  const int t = threadIdx.x;
  const int l0 = blockIdx.x * 64;
  const int head = blockIdx.y;
  const u16* src = vb + head * (2048 * 64) + l0 * 64;
  for (int c = t; c < 512; c += 256) {
    int l = c >> 3, dd = (c & 7) * 8;
    uint4 v = *(const uint4*)(src + l * 64 + dd);
    u16* d = &T[l][dd];
    ((uint2*)d)[0] = make_uint2(v.x, v.y);
    ((uint2*)d)[1] = make_uint2(v.z, v.w);
  }
  __syncthreads();
  u16* dsth = vtb + head * (64 * 2048);
  for (int c = t; c < 512; c += 256) {
    int d = c >> 3, lp = (c & 7) * 8;
    u16 tmp[8];
    for (int j = 0; j < 8; ++j) tmp[j] = T[lp + j][d];
    uint4 o;
    o.x = (unsigned)tmp[0] | ((unsigned)tmp[1] << 16);
    o.y = (unsigned)tmp[2] | ((unsigned)tmp[3] << 16);
    o.z = (unsigned)tmp[4] | ((unsigned)tmp[5] << 16);
    o.w = (unsigned)tmp[6] | ((unsigned)tmp[7] << 16);
    *(uint4*)(dsth + d * 2048 + l0 + lp) = o;
  }
}

// ---------------- flash attention: 32x32 swapped-QK^T, in-register softmax ----
// Wave owns 32 q-rows. S^T = mfma32(K,Q): lane (q=l&31, hi=l>>5) holds, per the
// verified C/D map, S^T[kv=crow(r,hi)][q] with crow(r,hi)=(r&3)+8*(r>>2)+4*hi.
// Softmax is in-lane + one lane^32 exchange. P->PV A-fragments built in-register
// with shfl_xor(32)+select (semantics-safe; round-4's permlane32_swap direction
// was the correctness bug). k-permutation invariance: P and V fragments both
// placed with the same assumed k-map, so the true A/B k-order cancels.
__global__ __launch_bounds__(256) void flash_attn(
    const u16* __restrict__ qb, const u16* __restrict__ kb, const u16* __restrict__ vtb,
    const float* __restrict__ mlog, float* __restrict__ out) {
  __shared__ u16 SM[4][64 * 64];   // [0,1]=K dbuf, [2,3]=V dbuf; prologue: Q in [0..1]

  const int t = threadIdx.x, lane = t & 63, w = t >> 6;
  const int hi = lane >> 5, l31 = lane & 31;
  const int q0 = blockIdx.x * 128;
  const int head = blockIdx.y;
  const int n = head >> 4, h = head & 15;

  const u16* qh = qb + head * (2048 * 64);
  const u16* kh = kb + head * (2048 * 64);
  const u16* vth = vtb + head * (64 * 2048);
  const float* mrow = mlog + n * 2048;

  // staging geometry (one gload_lds16 = 1KB = 8 rows of 128B)
  const int srow8 = lane >> 3;
  const int scolsw = ((lane & 7) ^ srow8) * 8;   // inverse-swizzled source col
  const int rsw = (lane & 7) * 8;                // read-side swizzle (row&7==lane&7)
  int fcolB[4];
  for (int dk = 0; dk < 4; ++dk) fcolB[dk] = (16 * dk + 8 * hi) ^ rsw;

  // ---- prologue: stage Q (128x64) into SM[0..1], read fragments, free it ----
  u16* QL = &SM[0][0];
  for (int i = 0; i < 4; ++i)
    gload_lds16(qh + (q0 + w * 32 + i * 8 + srow8) * 64 + scolsw, &QL[(w * 32 + i * 8) * 64]);
  __syncthreads();
  bf16x8 qf[4];
  for (int dk = 0; dk < 4; ++dk)
    qf[dk] = ldfrag(&QL[(w * 32 + l31) * 64 + fcolB[dk]]);
  __syncthreads();

  // stage K/V tile 0 into buffer 0
  {
    gload_lds16(kh + (w * 16 + srow8) * 64 + scolsw, &SM[0][w * 1024]);
    gload_lds16(kh + (w * 16 + 8 + srow8) * 64 + scolsw, &SM[0][w * 1024 + 512]);
    for (int i = 0; i < 2; ++i) {
      int dbase = w * 16 + i * 8;
      gload_lds16(vth + (dbase + srow8) * 2048 + scolsw, &SM[2][dbase * 64]);
    }
  }

  f32x16 o0, o1;
  for (int r = 0; r < 16; ++r) { o0[r] = 0.f; o1[r] = 0.f; }
  float m_ = -1e30f, lp = 0.f;

  for (int tt = 0; tt < 32; ++tt) {
    const int cur = tt & 1;
    const int kv0 = tt * 64;
    __syncthreads();   // buffer `cur` staged (barrier drains vmcnt)

    // stage next tile into other buffer (overlaps with compute)
    if (tt < 31) {
      const int kv1 = kv0 + 64;
      const u16* ksrc = kh + kv1 * 64;
      gload_lds16(ksrc + (w * 16 + srow8) * 64 + scolsw, &SM[cur ^ 1][w * 1024]);
      gload_lds16(ksrc + (w * 16 + 8 + srow8) * 64 + scolsw, &SM[cur ^ 1][w * 1024 + 512]);
      for (int i = 0; i < 2; ++i) {
        int dbase = w * 16 + i * 8;
        gload_lds16(vth + (dbase + srow8) * 2048 + kv1 + scolsw, &SM[2 + (cur ^ 1)][dbase * 64]);
      }
    }
    const u16* Kc = &SM[cur][0];
    const u16* Vc = &SM[2 + cur][0];

    // ---- S^T = K . Q^T, C initialized with mask (log2-domain, additive) ----
    f32x16 s1, s2;
    {
      const float* mb = mrow + kv0 + 4 * hi;
      for (int mq = 0; mq < 4; ++mq) {
        f32x4 ma = *(const f32x4*)(mb + 8 * mq);
        f32x4 mc = *(const f32x4*)(mb + 32 + 8 * mq);
        for (int e = 0; e < 4; ++e) { s1[4 * mq + e] = ma[e]; s2[4 * mq + e] = mc[e]; }
      }
    }
    for (int dk = 0; dk < 4; ++dk) {
      bf16x8 k0 = ldfrag(&Kc[l31 * 64 + fcolB[dk]]);
      bf16x8 k1 = ldfrag(&Kc[(32 + l31) * 64 + fcolB[dk]]);
      s1 = __builtin_amdgcn_mfma_f32_32x32x16_bf16(k0, qf[dk], s1, 0, 0, 0);
      s2 = __builtin_amdgcn_mfma_f32_32x32x16_bf16(k1, qf[dk], s2, 0, 0, 0);
    }

    // ---- online softmax, in-register (q = l31 for this lane) ----
    float pml = s1[0];
    for (int r = 1; r < 16; ++r) pml = fmaxf(pml, s1[r]);
    for (int r = 0; r < 16; ++r) pml = fmaxf(pml, s2[r]);

    if (!__all(pml <= m_ + 8.f)) {            // defer-max (T13, THR=8)
      float pm = fmaxf(pml, xor32_f(pml));    // full 64-kv max for q=l31
      float nm = fmaxf(m_, pm);
      float sc = exp2_fast(m_ - nm);
      m_ = nm;
      lp *= sc;
      // O rows are q=crow(r,hi) -> fetch that q's sc via bpermute
      for (int r = 0; r < 16; ++r) {
        float scr = bperm_f((r & 3) + 8 * (r >> 2) + 4 * hi, sc);
        o0[r] *= scr;
        o1[r] *= scr;
      }
    }

    // P = exp2(S - m), accumulate partial row-sum
    for (int r = 0; r < 16; ++r) {
      s1[r] = exp2_fast(s1[r] - m_);
      s2[r] = exp2_fast(s2[r] - m_);
      lp += s1[r] + s2[r];
    }

    // ---- P (C-layout) -> PV A-fragments, in-register ----
    // raw[m] packs kv pair (crow(2m,hi), crow(2m+1,hi)) for q=l31.
    // A-frag (assumed k-map: slot(hi,j) -> kv 16kc+8hi+j) word needs:
    //   w0 = hi? partner(raw2) : raw0     w1 = hi? partner(raw3) : raw1
    //   w2 = hi? raw2 : partner(raw0)     w3 = hi? raw3 : partner(raw1)
    unsigned raw[16];
    for (int mq = 0; mq < 8; ++mq) {
      raw[mq] = cvtpk(s1[2 * mq], s1[2 * mq + 1]);
      raw[8 + mq] = cvtpk(s2[2 * mq], s2[2 * mq + 1]);
    }
    union { unsigned u[16]; bf16x8 v[4]; } pw;
    for (int g = 0; g < 4; ++g) {
      unsigned a0 = raw[4 * g], a1 = raw[4 * g + 1];
      unsigned a2 = raw[4 * g + 2], a3 = raw[4 * g + 3];
      unsigned p0 = xor32_u(a0), p1 = xor32_u(a1);
      unsigned p2 = xor32_u(a2), p3 = xor32_u(a3);
      pw.u[4 * g + 0] = hi ? p2 : a0;
      pw.u[4 * g + 1] = hi ? p3 : a1;
      pw.u[4 * g + 2] = hi ? a2 : p0;
      pw.u[4 * g + 3] = hi ? a3 : p1;
    }

    // ---- O += P V  (B = V^T rows d, kv slices; same assumed k-map as P) ----
    for (int kc = 0; kc < 4; ++kc) {
      bf16x8 bv0 = ldfrag(&Vc[l31 * 64 + fcolB[kc]]);
      bf16x8 bv1 = ldfrag(&Vc[(32 + l31) * 64 + fcolB[kc]]);
      o0 = __builtin_amdgcn_mfma_f32_32x32x16_bf16(pw.v[kc], bv0, o0, 0, 0, 0);
      o1 = __builtin_amdgcn_mfma_f32_32x32x16_bf16(pw.v[kc], bv1, o1, 0, 0, 0);
    }
  }

  // ---- epilogue: combine partner sums, divide, store fp32 [N, L, E] ----
  float lpf = lp + xor32_f(lp);
  float inv = 1.0f / lpf;
  for (int r = 0; r < 16; ++r) {
    int qrow = (r & 3) + 8 * (r >> 2) + 4 * hi;
    float invr = bperm_f(qrow, inv);
    int q = q0 + w * 32 + qrow;
    float* ob = out + (n * 2048 + q) * 1024 + h * 64;
    ob[l31] = o0[r] * invr;
    ob[32 + l31] = o1[r] * invr;
  }
}

extern "C" void kernel_launch(void* const* d_in, const int* in_sizes, int n_in,
                              void* d_out, int out_size, void* d_ws, size_t ws_size,
                              hipStream_t stream) {
  const float* x = (const float*)d_in[0];
  const float* mask = (const float*)d_in[1];
  const float* Wq = (const float*)d_in[2];
  const float* bq = (const float*)d_in[3];
  const float* Wk = (const float*)d_in[4];
  const float* bk = (const float*)d_in[5];
  const float* Wv = (const float*)d_in[6];
  const float* bv = (const float*)d_in[7];
  float* out = (float*)d_out;

  u16* xb = (u16*)d_ws;                    // 8192*1024
  u16* wb = xb + 8192 * 1024;              // 3*1024*1024
  u16* qb = wb + 3 * 1024 * 1024;          // 64*2048*64 each
  u16* kb = qb + 64 * 2048 * 64;
  u16* vb = kb + 64 * 2048 * 64;
  u16* vtb = vb + 64 * 2048 * 64;
  float* mlog = (float*)wb;                // overwrites W-bf16 AFTER the GEMM

  cast_kernel<<<8192 * 1024 / 8 / 256, 256, 0, stream>>>(x, xb, 8192 * 1024 / 8);
  cast_kernel<<<1024 * 1024 / 8 / 256, 256, 0, stream>>>(Wq, wb, 1024 * 1024 / 8);
  cast_kernel<<<1024 * 1024 / 8 / 256, 256, 0, stream>>>(Wk, wb + 1024 * 1024, 1024 * 1024 / 8);
  cast_kernel<<<1024 * 1024 / 8 / 256, 256, 0, stream>>>(Wv, wb + 2 * 1024 * 1024, 1024 * 1024 / 8);
  qkv_gemm<<<dim3(64, 24), 256, 0, stream>>>(xb, wb, bq, bk, bv, qb, kb, vb);
  mask_scale<<<(4 * 2048 + 255) / 256, 256, 0, stream>>>(mask, mlog, 4 * 2048);
  transpose_v<<<dim3(32, 64), 256, 0, stream>>>(vb, vtb);
  flash_attn<<<dim3(16, 64), 256, 0, stream>>>(qb, kb, vtb, mlog, out);
}

// Round 7
// 209.476 us; speedup vs baseline: 1.7646x; 1.0395x over previous
//
#include <hip/hip_runtime.h>

#define DEV __device__ __forceinline__

typedef unsigned short u16;
typedef __attribute__((ext_vector_type(8))) __bf16 bf16x8;
typedef __attribute__((ext_vector_type(4))) float f32x4;
typedef __attribute__((ext_vector_type(16))) float f32x16;

#define LOG2E 1.44269504088896340736f

DEV u16 f2bf(float f) {
  union { float f; unsigned u; } v; v.f = f;
  unsigned r = v.u + 0x7FFFu + ((v.u >> 16) & 1u);
  return (u16)(r >> 16);
}

DEV float exp2_fast(float x) {
#if __has_builtin(__builtin_amdgcn_exp2f)
  return __builtin_amdgcn_exp2f(x);
#else
  float r;
  asm volatile("v_exp_f32 %0, %1" : "=v"(r) : "v"(x));
  return r;
#endif
}

// partner (lane^32) exchange -- proven primitives only (rounds 4/6 showed raw
// v_permlane32_swap asm is broken for us regardless of direction; see journal)
DEV float xor32_f(float v) { return __shfl_xor(v, 32, 64); }
DEV unsigned xor32_u(unsigned v) {
  return (unsigned)__shfl_xor((int)v, 32, 64);
}
DEV unsigned cvtpk(float lo, float hi) {
  unsigned r;
  asm volatile("v_cvt_pk_bf16_f32 %0, %1, %2" : "=v"(r) : "v"(lo), "v"(hi));
  return r;
}
DEV float bperm_f(int srclane, float v) {
  union { float f; int i; } u;
  u.f = v;
  u.i = __builtin_amdgcn_ds_bpermute(srclane * 4, u.i);
  return u.f;
}

template <typename T>
DEV void gload_lds16(const T* g, T* l) {
  __builtin_amdgcn_global_load_lds(
      (const __attribute__((address_space(1))) void*)(g),
      (__attribute__((address_space(3))) void*)(l),
      16, 0, 0);
}

DEV bf16x8 ldfrag(const u16* p) { return *(const bf16x8*)p; }

DEV void cast8(const float* __restrict__ in, u16* __restrict__ out) {
  float4 a = ((const float4*)in)[0];
  float4 b = ((const float4*)in)[1];
  uint4 o;
  o.x = (unsigned)f2bf(a.x) | ((unsigned)f2bf(a.y) << 16);
  o.y = (unsigned)f2bf(a.z) | ((unsigned)f2bf(a.w) << 16);
  o.z = (unsigned)f2bf(b.x) | ((unsigned)f2bf(b.y) << 16);
  o.w = (unsigned)f2bf(b.z) | ((unsigned)f2bf(b.w) << 16);
  *(uint4*)out = o;
}

// ---------------- fused prep: cast x, cast Wq/Wk/Wv, mask*log2e ----------------
__global__ __launch_bounds__(256) void prep_kernel(
    const float* __restrict__ x, const float* __restrict__ Wq,
    const float* __restrict__ Wk, const float* __restrict__ Wv,
    const float* __restrict__ mask,
    u16* __restrict__ xb, u16* __restrict__ wb, float* __restrict__ mlog) {
  const int i = blockIdx.x * 256 + threadIdx.x;
  const int NX = 8192 * 1024 / 8;        // 1048576
  const int NW = 1024 * 1024 / 8;        // 131072
  if (i < NX) {
    cast8(x + (long)i * 8, xb + (long)i * 8);
  } else if (i < NX + 3 * NW) {
    int j = i - NX;
    int sel = j / NW;                    // 0,1,2
    int jj = j - sel * NW;
    const float* W = (sel == 0) ? Wq : (sel == 1) ? Wk : Wv;
    cast8(W + (long)jj * 8, wb + (long)j * 8);
  } else {
    int j = i - NX - 3 * NW;             // 0..1023 (8192 mask floats / 8)
    float4 a = ((const float4*)mask)[2 * j];
    float4 b = ((const float4*)mask)[2 * j + 1];
    a.x *= LOG2E; a.y *= LOG2E; a.z *= LOG2E; a.w *= LOG2E;
    b.x *= LOG2E; b.y *= LOG2E; b.z *= LOG2E; b.w *= LOG2E;
    ((float4*)mlog)[2 * j] = a;
    ((float4*)mlog)[2 * j + 1] = b;
  }
}

// ---------------- fused QKV GEMM: [8192x1024] x W^T, m97-style ----------------
// V output is written TRANSPOSED ([NH][D][L], packed ushort4) -- replaces the
// separate transpose_v kernel and is better-coalesced than the strided
// scalar [NH][L][D] writes.
__global__ __launch_bounds__(256) void qkv_gemm(
    const u16* __restrict__ xb, const u16* __restrict__ wb,
    const float* __restrict__ bq, const float* __restrict__ bk, const float* __restrict__ bv,
    u16* __restrict__ qb, u16* __restrict__ kb, u16* __restrict__ vtb) {
  __shared__ u16 As[128 * 64];
  __shared__ u16 Bs[128 * 64];
  const int t = threadIdx.x, lane = t & 63, w = t >> 6;
  const int wm = w >> 1, wn = w & 1;
  const int m0 = blockIdx.x * 128;
  const int cb = blockIdx.y;
  const int wsel = cb >> 3;
  const int n0 = (cb & 7) * 128;
  const u16* W = wb + wsel * (1024 * 1024);
  const float* bias = (wsel == 0) ? bq : (wsel == 1) ? bk : bv;
  // Q gets 1/sqrt(D) AND log2(e) folded in (attention uses exp2 directly)
  const float scale = (wsel == 0) ? 0.125f * LOG2E : 1.0f;

  f32x4 acc[4][4];
  const f32x4 z4 = {0.f, 0.f, 0.f, 0.f};
  for (int i = 0; i < 4; ++i)
    for (int j = 0; j < 4; ++j) acc[i][j] = z4;

  const int srow = w * 32 + (lane >> 3);   // +i*8
  const int scol = (lane & 7) * 8;

  for (int k0 = 0; k0 < 1024; k0 += 64) {
    __syncthreads();
    for (int i = 0; i < 4; ++i) {
      gload_lds16(xb + (m0 + srow + i * 8) * 1024 + k0 + scol, &As[w * 2048 + i * 512]);
      gload_lds16(W + (n0 + srow + i * 8) * 1024 + k0 + scol, &Bs[w * 2048 + i * 512]);
    }
    __syncthreads();
    for (int ks = 0; ks < 2; ++ks) {
      bf16x8 a[4], b[4];
      for (int mi = 0; mi < 4; ++mi)
        a[mi] = ldfrag(&As[(wm * 64 + mi * 16 + (lane & 15)) * 64 + ks * 32 + (lane >> 4) * 8]);
      for (int ni = 0; ni < 4; ++ni)
        b[ni] = ldfrag(&Bs[(wn * 64 + ni * 16 + (lane & 15)) * 64 + ks * 32 + (lane >> 4) * 8]);
      for (int mi = 0; mi < 4; ++mi)
        for (int ni = 0; ni < 4; ++ni)
          acc[mi][ni] = __builtin_amdgcn_mfma_f32_16x16x32_bf16(a[mi], b[ni], acc[mi][ni], 0, 0, 0);
    }
  }
  // epilogue: scale + bias
  if (wsel == 2) {
    // V: write transposed [NH][D=64][L=2048], 4 consecutive lq -> ushort4
    for (int ni = 0; ni < 4; ++ni) {
      int col = n0 + wn * 64 + ni * 16 + (lane & 15);
      float bv_ = bias[col];
      int h = col >> 6, d = col & 63;
      for (int mi = 0; mi < 4; ++mi) {
        int gm = m0 + wm * 64 + mi * 16 + (lane >> 4) * 4;
        int nn = gm >> 11, lq = gm & 2047;
        ushort4 pk;
        pk.x = f2bf(acc[mi][ni][0] + bv_);
        pk.y = f2bf(acc[mi][ni][1] + bv_);
        pk.z = f2bf(acc[mi][ni][2] + bv_);
        pk.w = f2bf(acc[mi][ni][3] + bv_);
        *(ushort4*)(vtb + ((long)((nn << 4) + h) * 64 + d) * 2048 + lq) = pk;
      }
    }
  } else {
    u16* dst = (wsel == 0) ? qb : kb;
    for (int ni = 0; ni < 4; ++ni) {
      int col = n0 + wn * 64 + ni * 16 + (lane & 15);
      float bv_ = bias[col];
      int h = col >> 6, d = col & 63;
      for (int mi = 0; mi < 4; ++mi) {
        for (int r = 0; r < 4; ++r) {
          int gm = m0 + wm * 64 + mi * 16 + (lane >> 4) * 4 + r;
          int nn = gm >> 11, lq = gm & 2047;
          float val = acc[mi][ni][r] * scale + bv_;
          dst[(((nn << 4) + h) * 2048 + lq) * 64 + d] = f2bf(val);
        }
      }
    }
  }
}

// ---------------- flash attention: 32x32 swapped-QK^T, in-register softmax ----
// Wave owns 32 q-rows. S^T = mfma32(K,Q): lane (q=l&31, hi=l>>5) holds
// S^T[kv=crow(r,hi)][q], crow(r,hi)=(r&3)+8*(r>>2)+4*hi (verified C/D map).
// P->PV A-fragments via HALVED shfl_xor exchange (8 bpermutes/tile): each lane
// offers the word its partner needs, one xor32 moves both directions.
// XCD-aware block swizzle: 1024 blocks 1D, XCD x gets heads [8x,8x+8).
__global__ __launch_bounds__(256) void flash_attn(
    const u16* __restrict__ qb, const u16* __restrict__ kb, const u16* __restrict__ vtb,
    const float* __restrict__ mlog, float* __restrict__ out) {
  __shared__ u16 SM[4][64 * 64];   // [0,1]=K dbuf, [2,3]=V dbuf; prologue: Q in [0..1]

  const int t = threadIdx.x, lane = t & 63, w = t >> 6;
  const int hi = lane >> 5, l31 = lane & 31;
  const int bid = blockIdx.x;
  const int swz = (bid & 7) * 128 + (bid >> 3);   // bijective (1024 % 8 == 0)
  const int q0 = (swz & 15) * 128;
  const int head = swz >> 4;
  const int n = head >> 4, h = head & 15;

  const u16* qh = qb + head * (2048 * 64);
  const u16* kh = kb + head * (2048 * 64);
  const u16* vth = vtb + head * (64 * 2048);
  const float* mrow = mlog + n * 2048;

  // staging geometry (one gload_lds16 = 1KB = 8 rows of 128B)
  const int srow8 = lane >> 3;
  const int scolsw = ((lane & 7) ^ srow8) * 8;   // inverse-swizzled source col
  const int rsw = (lane & 7) * 8;                // read-side swizzle (row&7==lane&7)
  int fcolB[4];
  for (int dk = 0; dk < 4; ++dk) fcolB[dk] = (16 * dk + 8 * hi) ^ rsw;

  // ---- prologue: stage Q (128x64) into SM[0..1], read fragments, free it ----
  u16* QL = &SM[0][0];
  for (int i = 0; i < 4; ++i)
    gload_lds16(qh + (q0 + w * 32 + i * 8 + srow8) * 64 + scolsw, &QL[(w * 32 + i * 8) * 64]);
  __syncthreads();
  bf16x8 qf[4];
  for (int dk = 0; dk < 4; ++dk)
    qf[dk] = ldfrag(&QL[(w * 32 + l31) * 64 + fcolB[dk]]);
  __syncthreads();

  // stage K/V tile 0 into buffer 0
  {
    gload_lds16(kh + (w * 16 + srow8) * 64 + scolsw, &SM[0][w * 1024]);
    gload_lds16(kh + (w * 16 + 8 + srow8) * 64 + scolsw, &SM[0][w * 1024 + 512]);
    for (int i = 0; i < 2; ++i) {
      int dbase = w * 16 + i * 8;
      gload_lds16(vth + (dbase + srow8) * 2048 + scolsw, &SM[2][dbase * 64]);
    }
  }

  f32x16 o0, o1;
  for (int r = 0; r < 16; ++r) { o0[r] = 0.f; o1[r] = 0.f; }
  float m_ = -1e30f, lp = 0.f;

  for (int tt = 0; tt < 32; ++tt) {
    const int cur = tt & 1;
    const int kv0 = tt * 64;
    __syncthreads();   // buffer `cur` staged (barrier drains vmcnt)

    // stage next tile into other buffer (overlaps with compute)
    if (tt < 31) {
      const int kv1 = kv0 + 64;
      const u16* ksrc = kh + kv1 * 64;
      gload_lds16(ksrc + (w * 16 + srow8) * 64 + scolsw, &SM[cur ^ 1][w * 1024]);
      gload_lds16(ksrc + (w * 16 + 8 + srow8) * 64 + scolsw, &SM[cur ^ 1][w * 1024 + 512]);
      for (int i = 0; i < 2; ++i) {
        int dbase = w * 16 + i * 8;
        gload_lds16(vth + (dbase + srow8) * 2048 + kv1 + scolsw, &SM[2 + (cur ^ 1)][dbase * 64]);
      }
    }
    const u16* Kc = &SM[cur][0];
    const u16* Vc = &SM[2 + cur][0];

    // ---- S^T = K . Q^T, C initialized with mask (log2-domain, additive) ----
    f32x16 s1, s2;
    {
      const float* mb = mrow + kv0 + 4 * hi;
      for (int mq = 0; mq < 4; ++mq) {
        f32x4 ma = *(const f32x4*)(mb + 8 * mq);
        f32x4 mc = *(const f32x4*)(mb + 32 + 8 * mq);
        for (int e = 0; e < 4; ++e) { s1[4 * mq + e] = ma[e]; s2[4 * mq + e] = mc[e]; }
      }
    }
    __builtin_amdgcn_s_setprio(1);
    for (int dk = 0; dk < 4; ++dk) {
      bf16x8 k0 = ldfrag(&Kc[l31 * 64 + fcolB[dk]]);
      bf16x8 k1 = ldfrag(&Kc[(32 + l31) * 64 + fcolB[dk]]);
      s1 = __builtin_amdgcn_mfma_f32_32x32x16_bf16(k0, qf[dk], s1, 0, 0, 0);
      s2 = __builtin_amdgcn_mfma_f32_32x32x16_bf16(k1, qf[dk], s2, 0, 0, 0);
    }
    __builtin_amdgcn_s_setprio(0);

    // ---- online softmax, in-register (q = l31 for this lane), tree max ----
    float tm[16];
#pragma unroll
    for (int r = 0; r < 16; ++r) tm[r] = fmaxf(s1[r], s2[r]);
#pragma unroll
    for (int st = 8; st >= 1; st >>= 1)
#pragma unroll
      for (int r = 0; r < st; ++r) tm[r] = fmaxf(tm[r], tm[r + st]);
    float pml = tm[0];

    if (!__all(pml <= m_ + 8.f)) {            // defer-max (T13, THR=8)
      float pm = fmaxf(pml, xor32_f(pml));    // full 64-kv max for q=l31
      float nm = fmaxf(m_, pm);
      float sc = exp2_fast(m_ - nm);
      m_ = nm;
      lp *= sc;
      // O rows are q=crow(r,hi) -> fetch that q's sc via bpermute
      for (int r = 0; r < 16; ++r) {
        float scr = bperm_f((r & 3) + 8 * (r >> 2) + 4 * hi, sc);
        o0[r] *= scr;
        o1[r] *= scr;
      }
    }

    // P = exp2(S - m); tree-sum the partial row-sum
#pragma unroll
    for (int r = 0; r < 16; ++r) {
      s1[r] = exp2_fast(s1[r] - m_);
      s2[r] = exp2_fast(s2[r] - m_);
    }
    float ts[16];
#pragma unroll
    for (int r = 0; r < 16; ++r) ts[r] = s1[r] + s2[r];
#pragma unroll
    for (int st = 8; st >= 1; st >>= 1)
#pragma unroll
      for (int r = 0; r < st; ++r) ts[r] += ts[r + st];
    lp += ts[0];

    // ---- P (C-layout) -> PV A-fragments, halved shfl_xor exchange ----
    // needed: pw0=[a0.lo|a2.lo^], pw1=[a1.lo|a3.lo^], pw2=[a0.hi_|a2.hi],
    //         pw3=[a1.hi_|a3.hi]  (round-5-verified select formulas)
    unsigned raw[16];
#pragma unroll
    for (int mq = 0; mq < 8; ++mq) {
      raw[mq] = cvtpk(s1[2 * mq], s1[2 * mq + 1]);
      raw[8 + mq] = cvtpk(s2[2 * mq], s2[2 * mq + 1]);
    }
    union { unsigned u[16]; bf16x8 v[4]; } pw;
#pragma unroll
    for (int g = 0; g < 4; ++g) {
      unsigned a0 = raw[4 * g], a1 = raw[4 * g + 1];
      unsigned a2 = raw[4 * g + 2], a3 = raw[4 * g + 3];
      unsigned v0 = hi ? a0 : a2;      // offer what the partner needs
      unsigned v1 = hi ? a1 : a3;
      unsigned x0 = xor32_u(v0);       // hi=0: p0 ; hi=1: p2
      unsigned x1 = xor32_u(v1);       // hi=0: p1 ; hi=1: p3
      pw.u[4 * g + 0] = hi ? x0 : a0;
      pw.u[4 * g + 1] = hi ? x1 : a1;
      pw.u[4 * g + 2] = hi ? a2 : x0;
      pw.u[4 * g + 3] = hi ? a3 : x1;
    }

    // ---- O += P V  (B = V^T rows d, kv slices; same assumed k-map as P) ----
    __builtin_amdgcn_s_setprio(1);
    for (int kc = 0; kc < 4; ++kc) {
      bf16x8 bv0 = ldfrag(&Vc[l31 * 64 + fcolB[kc]]);
      bf16x8 bv1 = ldfrag(&Vc[(32 + l31) * 64 + fcolB[kc]]);
      o0 = __builtin_amdgcn_mfma_f32_32x32x16_bf16(pw.v[kc], bv0, o0, 0, 0, 0);
      o1 = __builtin_amdgcn_mfma_f32_32x32x16_bf16(pw.v[kc], bv1, o1, 0, 0, 0);
    }
    __builtin_amdgcn_s_setprio(0);
  }

  // ---- epilogue: combine partner sums, divide, store fp32 [N, L, E] ----
  float lpf = lp + xor32_f(lp);
  float inv = 1.0f / lpf;
  for (int r = 0; r < 16; ++r) {
    int qrow = (r & 3) + 8 * (r >> 2) + 4 * hi;
    float invr = bperm_f(qrow, inv);
    int q = q0 + w * 32 + qrow;
    float* ob = out + (n * 2048 + q) * 1024 + h * 64;
    ob[l31] = o0[r] * invr;
    ob[32 + l31] = o1[r] * invr;
  }
}

extern "C" void kernel_launch(void* const* d_in, const int* in_sizes, int n_in,
                              void* d_out, int out_size, void* d_ws, size_t ws_size,
                              hipStream_t stream) {
  const float* x = (const float*)d_in[0];
  const float* mask = (const float*)d_in[1];
  const float* Wq = (const float*)d_in[2];
  const float* bq = (const float*)d_in[3];
  const float* Wk = (const float*)d_in[4];
  const float* bk = (const float*)d_in[5];
  const float* Wv = (const float*)d_in[6];
  const float* bv = (const float*)d_in[7];
  float* out = (float*)d_out;

  u16* xb = (u16*)d_ws;                    // 8192*1024
  u16* wb = xb + 8192 * 1024;              // 3*1024*1024
  u16* qb = wb + 3 * 1024 * 1024;          // 64*2048*64 each
  u16* kb = qb + 64 * 2048 * 64;
  u16* vtb = kb + 64 * 2048 * 64;          // V written transposed by the GEMM
  float* mlog = (float*)(vtb + 64 * 2048 * 64);   // 8192 floats

  // prep: cast x (1048576 u8-units) + cast W (393216) + mask (1024) = 1442816
  prep_kernel<<<1442816 / 256, 256, 0, stream>>>(x, Wq, Wk, Wv, mask, xb, wb, mlog);
  qkv_gemm<<<dim3(64, 24), 256, 0, stream>>>(xb, wb, bq, bk, bv, qb, kb, vtb);
  flash_attn<<<1024, 256, 0, stream>>>(qb, kb, vtb, mlog, out);
}

// Round 8
// 207.541 us; speedup vs baseline: 1.7811x; 1.0093x over previous
//
#include <hip/hip_runtime.h>

#define DEV __device__ __forceinline__

typedef unsigned short u16;
typedef __attribute__((ext_vector_type(8))) __bf16 bf16x8;
typedef __attribute__((ext_vector_type(4))) float f32x4;
typedef __attribute__((ext_vector_type(16))) float f32x16;

#define LOG2E 1.44269504088896340736f

DEV u16 f2bf(float f) {
  union { float f; unsigned u; } v; v.f = f;
  unsigned r = v.u + 0x7FFFu + ((v.u >> 16) & 1u);
  return (u16)(r >> 16);
}

DEV float exp2_fast(float x) {
#if __has_builtin(__builtin_amdgcn_exp2f)
  return __builtin_amdgcn_exp2f(x);
#else
  float r;
  asm volatile("v_exp_f32 %0, %1" : "=v"(r) : "v"(x));
  return r;
#endif
}

// partner (lane^32) exchange -- proven primitives only (rounds 4/6: raw
// v_permlane32_swap asm failed both directions; do not retry)
DEV float xor32_f(float v) { return __shfl_xor(v, 32, 64); }
DEV unsigned xor32_u(unsigned v) {
  return (unsigned)__shfl_xor((int)v, 32, 64);
}
DEV unsigned cvtpk(float lo, float hi) {
  unsigned r;
  asm volatile("v_cvt_pk_bf16_f32 %0, %1, %2" : "=v"(r) : "v"(lo), "v"(hi));
  return r;
}
DEV float bperm_f(int srclane, float v) {
  union { float f; int i; } u;
  u.f = v;
  u.i = __builtin_amdgcn_ds_bpermute(srclane * 4, u.i);
  return u.f;
}

template <typename T>
DEV void gload_lds16(const T* g, T* l) {
  __builtin_amdgcn_global_load_lds(
      (const __attribute__((address_space(1))) void*)(g),
      (__attribute__((address_space(3))) void*)(l),
      16, 0, 0);
}

DEV bf16x8 ldfrag(const u16* p) { return *(const bf16x8*)p; }

DEV void cast8(const float* __restrict__ in, u16* __restrict__ out) {
  float4 a = ((const float4*)in)[0];
  float4 b = ((const float4*)in)[1];
  uint4 o;
  o.x = (unsigned)f2bf(a.x) | ((unsigned)f2bf(a.y) << 16);
  o.y = (unsigned)f2bf(a.z) | ((unsigned)f2bf(a.w) << 16);
  o.z = (unsigned)f2bf(b.x) | ((unsigned)f2bf(b.y) << 16);
  o.w = (unsigned)f2bf(b.z) | ((unsigned)f2bf(b.w) << 16);
  *(uint4*)out = o;
}

// ---------------- fused prep: cast x, cast Wq/Wk/Wv, mask*log2e ----------------
__global__ __launch_bounds__(256) void prep_kernel(
    const float* __restrict__ x, const float* __restrict__ Wq,
    const float* __restrict__ Wk, const float* __restrict__ Wv,
    const float* __restrict__ mask,
    u16* __restrict__ xb, u16* __restrict__ wb, float* __restrict__ mlog) {
  const int i = blockIdx.x * 256 + threadIdx.x;
  const int NX = 8192 * 1024 / 8;        // 1048576
  const int NW = 1024 * 1024 / 8;        // 131072
  if (i < NX) {
    cast8(x + (long)i * 8, xb + (long)i * 8);
  } else if (i < NX + 3 * NW) {
    int j = i - NX;
    int sel = j / NW;                    // 0,1,2
    int jj = j - sel * NW;
    const float* W = (sel == 0) ? Wq : (sel == 1) ? Wk : Wv;
    cast8(W + (long)jj * 8, wb + (long)j * 8);
  } else {
    int j = i - NX - 3 * NW;             // 0..1023 (8192 mask floats / 8)
    float4 a = ((const float4*)mask)[2 * j];
    float4 b = ((const float4*)mask)[2 * j + 1];
    a.x *= LOG2E; a.y *= LOG2E; a.z *= LOG2E; a.w *= LOG2E;
    b.x *= LOG2E; b.y *= LOG2E; b.z *= LOG2E; b.w *= LOG2E;
    ((float4*)mlog)[2 * j] = a;
    ((float4*)mlog)[2 * j + 1] = b;
  }
}

// ---------------- fused QKV GEMM: [8192x1024] x W^T, m97-style ----------------
// V output written TRANSPOSED ([NH][D][L], packed ushort4).
__global__ __launch_bounds__(256) void qkv_gemm(
    const u16* __restrict__ xb, const u16* __restrict__ wb,
    const float* __restrict__ bq, const float* __restrict__ bk, const float* __restrict__ bv,
    u16* __restrict__ qb, u16* __restrict__ kb, u16* __restrict__ vtb) {
  __shared__ u16 As[128 * 64];
  __shared__ u16 Bs[128 * 64];
  const int t = threadIdx.x, lane = t & 63, w = t >> 6;
  const int wm = w >> 1, wn = w & 1;
  const int m0 = blockIdx.x * 128;
  const int cb = blockIdx.y;
  const int wsel = cb >> 3;
  const int n0 = (cb & 7) * 128;
  const u16* W = wb + wsel * (1024 * 1024);
  const float* bias = (wsel == 0) ? bq : (wsel == 1) ? bk : bv;
  // Q gets 1/sqrt(D) AND log2(e) folded in (attention uses exp2 directly)
  const float scale = (wsel == 0) ? 0.125f * LOG2E : 1.0f;

  f32x4 acc[4][4];
  const f32x4 z4 = {0.f, 0.f, 0.f, 0.f};
  for (int i = 0; i < 4; ++i)
    for (int j = 0; j < 4; ++j) acc[i][j] = z4;

  const int srow = w * 32 + (lane >> 3);   // +i*8
  const int scol = (lane & 7) * 8;

  for (int k0 = 0; k0 < 1024; k0 += 64) {
    __syncthreads();
    for (int i = 0; i < 4; ++i) {
      gload_lds16(xb + (m0 + srow + i * 8) * 1024 + k0 + scol, &As[w * 2048 + i * 512]);
      gload_lds16(W + (n0 + srow + i * 8) * 1024 + k0 + scol, &Bs[w * 2048 + i * 512]);
    }
    __syncthreads();
    for (int ks = 0; ks < 2; ++ks) {
      bf16x8 a[4], b[4];
      for (int mi = 0; mi < 4; ++mi)
        a[mi] = ldfrag(&As[(wm * 64 + mi * 16 + (lane & 15)) * 64 + ks * 32 + (lane >> 4) * 8]);
      for (int ni = 0; ni < 4; ++ni)
        b[ni] = ldfrag(&Bs[(wn * 64 + ni * 16 + (lane & 15)) * 64 + ks * 32 + (lane >> 4) * 8]);
      for (int mi = 0; mi < 4; ++mi)
        for (int ni = 0; ni < 4; ++ni)
          acc[mi][ni] = __builtin_amdgcn_mfma_f32_16x16x32_bf16(a[mi], b[ni], acc[mi][ni], 0, 0, 0);
    }
  }
  // epilogue: scale + bias
  if (wsel == 2) {
    // V: write transposed [NH][D=64][L=2048], 4 consecutive lq -> ushort4
    for (int ni = 0; ni < 4; ++ni) {
      int col = n0 + wn * 64 + ni * 16 + (lane & 15);
      float bv_ = bias[col];
      int h = col >> 6, d = col & 63;
      for (int mi = 0; mi < 4; ++mi) {
        int gm = m0 + wm * 64 + mi * 16 + (lane >> 4) * 4;
        int nn = gm >> 11, lq = gm & 2047;
        ushort4 pk;
        pk.x = f2bf(acc[mi][ni][0] + bv_);
        pk.y = f2bf(acc[mi][ni][1] + bv_);
        pk.z = f2bf(acc[mi][ni][2] + bv_);
        pk.w = f2bf(acc[mi][ni][3] + bv_);
        *(ushort4*)(vtb + ((long)((nn << 4) + h) * 64 + d) * 2048 + lq) = pk;
      }
    }
  } else {
    u16* dst = (wsel == 0) ? qb : kb;
    for (int ni = 0; ni < 4; ++ni) {
      int col = n0 + wn * 64 + ni * 16 + (lane & 15);
      float bv_ = bias[col];
      int h = col >> 6, d = col & 63;
      for (int mi = 0; mi < 4; ++mi) {
        for (int r = 0; r < 4; ++r) {
          int gm = m0 + wm * 64 + mi * 16 + (lane >> 4) * 4 + r;
          int nn = gm >> 11, lq = gm & 2047;
          float val = acc[mi][ni][r] * scale + bv_;
          dst[(((nn << 4) + h) * 2048 + lq) * 64 + d] = f2bf(val);
        }
      }
    }
  }
}

// ---------------- flash attention: 32x32 swapped-QK^T, in-register softmax ----
// NEW this round: the mask row (2048 floats, 8KB) is staged to LDS once in the
// prologue. Per-tile mask C-init reads are ds_read (lgkm counter) instead of
// VMEM -- so NO vmem load is consumed inside an iteration, and the vmcnt FIFO
// never forces the K/V global_load_lds prefetch to drain early. (Round-7 had
// mask VMEM loads issued after the staging loads; waiting on them drained the
// whole staging queue every tile, defeating the overlap.)
__global__ __launch_bounds__(256) void flash_attn(
    const u16* __restrict__ qb, const u16* __restrict__ kb, const u16* __restrict__ vtb,
    const float* __restrict__ mlog, float* __restrict__ out) {
  __shared__ u16 SM[4][64 * 64];   // [0,1]=K dbuf, [2,3]=V dbuf; prologue: Q in [0..1]
  __shared__ float MK[2048];       // mask row * log2e, staged once

  const int t = threadIdx.x, lane = t & 63, w = t >> 6;
  const int hi = lane >> 5, l31 = lane & 31;
  const int bid = blockIdx.x;
  const int swz = (bid & 7) * 128 + (bid >> 3);   // bijective (1024 % 8 == 0)
  const int q0 = (swz & 15) * 128;
  const int head = swz >> 4;
  const int n = head >> 4, h = head & 15;

  const u16* qh = qb + head * (2048 * 64);
  const u16* kh = kb + head * (2048 * 64);
  const u16* vth = vtb + head * (64 * 2048);
  const float* mrow = mlog + n * 2048;

  // staging geometry (one gload_lds16 = 1KB = 8 rows of 128B)
  const int srow8 = lane >> 3;
  const int scolsw = ((lane & 7) ^ srow8) * 8;   // inverse-swizzled source col
  const int rsw = (lane & 7) * 8;                // read-side swizzle (row&7==lane&7)
  int fcolB[4];
  for (int dk = 0; dk < 4; ++dk) fcolB[dk] = (16 * dk + 8 * hi) ^ rsw;

  // ---- prologue: stage Q (128x64) into SM[0..1] + mask row into MK ----
  u16* QL = &SM[0][0];
  for (int i = 0; i < 4; ++i)
    gload_lds16(qh + (q0 + w * 32 + i * 8 + srow8) * 64 + scolsw, &QL[(w * 32 + i * 8) * 64]);
  // mask: 2048 floats = 8 chunks of 256 floats (64 lanes x 16B); wave w does 2
  for (int i = 0; i < 2; ++i) {
    int chunk = w * 2 + i;
    gload_lds16(mrow + chunk * 256 + lane * 4, &MK[chunk * 256]);
  }
  __syncthreads();
  bf16x8 qf[4];
  for (int dk = 0; dk < 4; ++dk)
    qf[dk] = ldfrag(&QL[(w * 32 + l31) * 64 + fcolB[dk]]);
  __syncthreads();

  // stage K/V tile 0 into buffer 0
  {
    gload_lds16(kh + (w * 16 + srow8) * 64 + scolsw, &SM[0][w * 1024]);
    gload_lds16(kh + (w * 16 + 8 + srow8) * 64 + scolsw, &SM[0][w * 1024 + 512]);
    for (int i = 0; i < 2; ++i) {
      int dbase = w * 16 + i * 8;
      gload_lds16(vth + (dbase + srow8) * 2048 + scolsw, &SM[2][dbase * 64]);
    }
  }

  f32x16 o0, o1;
  for (int r = 0; r < 16; ++r) { o0[r] = 0.f; o1[r] = 0.f; }
  float m_ = -1e30f, lp = 0.f;

  for (int tt = 0; tt < 32; ++tt) {
    const int cur = tt & 1;
    const int kv0 = tt * 64;
    __syncthreads();   // buffer `cur` staged (barrier drains vmcnt)

    // stage next tile into other buffer -- these loads are consumed only at
    // the NEXT barrier; nothing below waits on vmcnt
    if (tt < 31) {
      const int kv1 = kv0 + 64;
      const u16* ksrc = kh + kv1 * 64;
      gload_lds16(ksrc + (w * 16 + srow8) * 64 + scolsw, &SM[cur ^ 1][w * 1024]);
      gload_lds16(ksrc + (w * 16 + 8 + srow8) * 64 + scolsw, &SM[cur ^ 1][w * 1024 + 512]);
      for (int i = 0; i < 2; ++i) {
        int dbase = w * 16 + i * 8;
        gload_lds16(vth + (dbase + srow8) * 2048 + kv1 + scolsw, &SM[2 + (cur ^ 1)][dbase * 64]);
      }
    }
    const u16* Kc = &SM[cur][0];
    const u16* Vc = &SM[2 + cur][0];

    // ---- S^T = K . Q^T, C initialized with mask from LDS (broadcast reads) ----
    f32x16 s1, s2;
    {
      const float* mb = &MK[kv0 + 4 * hi];
      for (int mq = 0; mq < 4; ++mq) {
        f32x4 ma = *(const f32x4*)(mb + 8 * mq);
        f32x4 mc = *(const f32x4*)(mb + 32 + 8 * mq);
        for (int e = 0; e < 4; ++e) { s1[4 * mq + e] = ma[e]; s2[4 * mq + e] = mc[e]; }
      }
    }
    __builtin_amdgcn_s_setprio(1);
    for (int dk = 0; dk < 4; ++dk) {
      bf16x8 k0 = ldfrag(&Kc[l31 * 64 + fcolB[dk]]);
      bf16x8 k1 = ldfrag(&Kc[(32 + l31) * 64 + fcolB[dk]]);
      s1 = __builtin_amdgcn_mfma_f32_32x32x16_bf16(k0, qf[dk], s1, 0, 0, 0);
      s2 = __builtin_amdgcn_mfma_f32_32x32x16_bf16(k1, qf[dk], s2, 0, 0, 0);
    }
    __builtin_amdgcn_s_setprio(0);

    // ---- online softmax, in-register (q = l31 for this lane), tree max ----
    float tm[16];
#pragma unroll
    for (int r = 0; r < 16; ++r) tm[r] = fmaxf(s1[r], s2[r]);
#pragma unroll
    for (int st = 8; st >= 1; st >>= 1)
#pragma unroll
      for (int r = 0; r < st; ++r) tm[r] = fmaxf(tm[r], tm[r + st]);
    float pml = tm[0];

    if (!__all(pml <= m_ + 8.f)) {            // defer-max (T13, THR=8)
      float pm = fmaxf(pml, xor32_f(pml));    // full 64-kv max for q=l31
      float nm = fmaxf(m_, pm);
      float sc = exp2_fast(m_ - nm);
      m_ = nm;
      lp *= sc;
      // O rows are q=crow(r,hi) -> fetch that q's sc via bpermute
      for (int r = 0; r < 16; ++r) {
        float scr = bperm_f((r & 3) + 8 * (r >> 2) + 4 * hi, sc);
        o0[r] *= scr;
        o1[r] *= scr;
      }
    }

    // P = exp2(S - m); tree-sum the partial row-sum
#pragma unroll
    for (int r = 0; r < 16; ++r) {
      s1[r] = exp2_fast(s1[r] - m_);
      s2[r] = exp2_fast(s2[r] - m_);
    }
    float ts[16];
#pragma unroll
    for (int r = 0; r < 16; ++r) ts[r] = s1[r] + s2[r];
#pragma unroll
    for (int st = 8; st >= 1; st >>= 1)
#pragma unroll
      for (int r = 0; r < st; ++r) ts[r] += ts[r + st];
    lp += ts[0];

    // ---- P (C-layout) -> PV A-fragments, halved shfl_xor exchange ----
    unsigned raw[16];
#pragma unroll
    for (int mq = 0; mq < 8; ++mq) {
      raw[mq] = cvtpk(s1[2 * mq], s1[2 * mq + 1]);
      raw[8 + mq] = cvtpk(s2[2 * mq], s2[2 * mq + 1]);
    }
    union { unsigned u[16]; bf16x8 v[4]; } pw;
#pragma unroll
    for (int g = 0; g < 4; ++g) {
      unsigned a0 = raw[4 * g], a1 = raw[4 * g + 1];
      unsigned a2 = raw[4 * g + 2], a3 = raw[4 * g + 3];
      unsigned v0 = hi ? a0 : a2;      // offer what the partner needs
      unsigned v1 = hi ? a1 : a3;
      unsigned x0 = xor32_u(v0);       // hi=0: p0 ; hi=1: p2
      unsigned x1 = xor32_u(v1);       // hi=0: p1 ; hi=1: p3
      pw.u[4 * g + 0] = hi ? x0 : a0;
      pw.u[4 * g + 1] = hi ? x1 : a1;
      pw.u[4 * g + 2] = hi ? a2 : x0;
      pw.u[4 * g + 3] = hi ? a3 : x1;
    }

    // ---- O += P V  (B = V^T rows d, kv slices; same assumed k-map as P) ----
    __builtin_amdgcn_s_setprio(1);
    for (int kc = 0; kc < 4; ++kc) {
      bf16x8 bv0 = ldfrag(&Vc[l31 * 64 + fcolB[kc]]);
      bf16x8 bv1 = ldfrag(&Vc[(32 + l31) * 64 + fcolB[kc]]);
      o0 = __builtin_amdgcn_mfma_f32_32x32x16_bf16(pw.v[kc], bv0, o0, 0, 0, 0);
      o1 = __builtin_amdgcn_mfma_f32_32x32x16_bf16(pw.v[kc], bv1, o1, 0, 0, 0);
    }
    __builtin_amdgcn_s_setprio(0);
  }

  // ---- epilogue: combine partner sums, divide, store fp32 [N, L, E] ----
  float lpf = lp + xor32_f(lp);
  float inv = 1.0f / lpf;
  for (int r = 0; r < 16; ++r) {
    int qrow = (r & 3) + 8 * (r >> 2) + 4 * hi;
    float invr = bperm_f(qrow, inv);
    int q = q0 + w * 32 + qrow;
    float* ob = out + (n * 2048 + q) * 1024 + h * 64;
    ob[l31] = o0[r] * invr;
    ob[32 + l31] = o1[r] * invr;
  }
}

extern "C" void kernel_launch(void* const* d_in, const int* in_sizes, int n_in,
                              void* d_out, int out_size, void* d_ws, size_t ws_size,
                              hipStream_t stream) {
  const float* x = (const float*)d_in[0];
  const float* mask = (const float*)d_in[1];
  const float* Wq = (const float*)d_in[2];
  const float* bq = (const float*)d_in[3];
  const float* Wk = (const float*)d_in[4];
  const float* bk = (const float*)d_in[5];
  const float* Wv = (const float*)d_in[6];
  const float* bv = (const float*)d_in[7];
  float* out = (float*)d_out;

  u16* xb = (u16*)d_ws;                    // 8192*1024
  u16* wb = xb + 8192 * 1024;              // 3*1024*1024
  u16* qb = wb + 3 * 1024 * 1024;          // 64*2048*64 each
  u16* kb = qb + 64 * 2048 * 64;
  u16* vtb = kb + 64 * 2048 * 64;          // V written transposed by the GEMM
  float* mlog = (float*)(vtb + 64 * 2048 * 64);   // 8192 floats

  // prep: cast x (1048576 u8-units) + cast W (393216) + mask (1024) = 1442816
  prep_kernel<<<1442816 / 256, 256, 0, stream>>>(x, Wq, Wk, Wv, mask, xb, wb, mlog);
  qkv_gemm<<<dim3(64, 24), 256, 0, stream>>>(xb, wb, bq, bk, bv, qb, kb, vtb);
  flash_attn<<<1024, 256, 0, stream>>>(qb, kb, vtb, mlog, out);
}